// Round 5
// baseline (3609.381 us; speedup 1.0000x reference)
//
#include <hip/hip_runtime.h>
#include <cstdint>
#include <cstddef>

// Attention_41231686042092: ViT attention + softmax sparsification (per-(b,h)
// exact median threshold via radix select on f32 bit patterns) + diag-based
// token pruning + projection. All f32 (ranking needs exact-index fidelity).
//
// Round-5:
//  * qkv/proj: 128x128 tile, 8x8 microtile (2.0 FLOP/LDS-byte vs 1.33).
//  * stats+hist-L1 fused (logits held in 160 VGPRs) -> one less QK pass.
//  * candidate compaction: pass B appends pfx1-matching values to a compact
//    buffer; select_mid radix-selects remaining 20 bits over candidates ->
//    L3 QK pass + select become flag-gated no-ops (overflow fallback kept).
// Every logit is a single ascending-k fmaf chain (fma4) -> bit-identical
// across all passes; M/S loaded from the same globals everywhere.

namespace {
constexpr int B_  = 16;
constexpr int N_  = 577;
constexpr int C_  = 768;
constexpr int H_  = 12;
constexpr int HD_ = 64;
constexpr int BH_ = B_ * H_;            // 192
constexpr int KK_ = N_ - 57;            // 520 kept tokens
constexpr unsigned KIDX_ = 166464u;     // int(N*N*0.5), 0-based desc rank
constexpr int M1_ = B_ * N_;            // 9232
constexpr int M2_ = B_ * KK_;           // 8320
constexpr int CAPMAX_ = 24576;          // candidate cap per (b,h)
constexpr int NT_ = 5;                  // col tiles of 128 covering 577
}

__device__ __forceinline__ void fma4(const float4& a, const float4& b, float& acc) {
  acc = __builtin_fmaf(a.x, b.x, acc);
  acc = __builtin_fmaf(a.y, b.y, acc);
  acc = __builtin_fmaf(a.z, b.z, acc);
  acc = __builtin_fmaf(a.w, b.w, acc);
}

// ---------------------------------------------------------------- QKV GEMM
// Y = X @ W^T ; X:[M1,768], W:[2304,768]. 128x128 tile, 8x8 microtile, BK=32.
__global__ __launch_bounds__(256) void qkv_gemm(
    const float* __restrict__ X, const float* __restrict__ W,
    float* __restrict__ qb, float* __restrict__ kb, float* __restrict__ vb) {
  __shared__ __align__(16) float Xs[128][36];
  __shared__ __align__(16) float Ws2[128][36];
  const int m0 = blockIdx.x * 128;
  const int n0 = blockIdx.y * 128;
  const int t = threadIdx.x;
  const int tx = t & 15, ty = t >> 4;
  float acc[8][8] = {};
  for (int k0 = 0; k0 < 768; k0 += 32) {
    __syncthreads();
    {
      const int c = t & 7, r0 = t >> 3;  // 8 float4-cols, 32 rows per pass
#pragma unroll
      for (int s = 0; s < 4; s++) {
        int r = r0 + 32 * s;
        int gm = m0 + r;
        float4 v = make_float4(0.f, 0.f, 0.f, 0.f);
        if (gm < M1_) v = *(const float4*)&X[(size_t)gm * 768 + k0 + 4 * c];
        *(float4*)&Xs[r][4 * c] = v;
        float4 w = *(const float4*)&W[(size_t)(n0 + r) * 768 + k0 + 4 * c];
        *(float4*)&Ws2[r][4 * c] = w;
      }
    }
    __syncthreads();
#pragma unroll
    for (int d4 = 0; d4 < 8; d4++) {
      float4 a4[8], b4[8];
#pragma unroll
      for (int i = 0; i < 8; i++) a4[i] = *(const float4*)&Xs[tx + 16 * i][4 * d4];
#pragma unroll
      for (int j = 0; j < 8; j++) b4[j] = *(const float4*)&Ws2[ty + 16 * j][4 * d4];
#pragma unroll
      for (int i = 0; i < 8; i++)
#pragma unroll
        for (int j = 0; j < 8; j++) fma4(a4[i], b4[j], acc[i][j]);
    }
  }
  for (int i = 0; i < 8; i++) {
    int gm = m0 + tx + 16 * i;
    if (gm >= M1_) continue;
    int b = gm / N_, n = gm % N_;
    for (int j = 0; j < 8; j++) {
      int gn = n0 + ty + 16 * j;
      int which = gn / C_, rem = gn % C_;
      int h = rem >> 6, d = rem & 63;
      float* dst = (which == 0) ? qb : (which == 1) ? kb : vb;
      dst[(((size_t)(b * H_ + h)) * N_ + n) * HD_ + d] = acc[i][j];
    }
  }
}

// ------------------------------------- pass A: stats + hist-L1 (fused)
// 64 q-rows/block x 5 col-tiles of 128; logits kept in registers
// (l[5][4][8] = 160 VGPR). Row max/sum reduced from registers, then the
// same registers are binned into the 12-bit histogram.
__global__ __launch_bounds__(256) void stats_hist1(
    const float* __restrict__ qb, const float* __restrict__ kb,
    float* __restrict__ rowmax_g, float* __restrict__ rowsum_g,
    float* __restrict__ ldiag, unsigned* __restrict__ hist1) {
  __shared__ __align__(16) float Qs[64][68];
  __shared__ __align__(16) float Ksf[128][68];
  __shared__ unsigned hloc[4096];
  __shared__ float Mrow[64], Srow[64];
  const int bh = blockIdx.x;
  const int q0 = blockIdx.y * 64;
  const int t = threadIdx.x;
  const int tx = t & 15, ty = t >> 4;
  for (int i = t; i < 4096; i += 256) hloc[i] = 0u;
  {
    const int c = t & 15, r0 = t >> 4;
#pragma unroll
    for (int s = 0; s < 4; s++) {
      int r = r0 + 16 * s;
      int gq = q0 + r;
      float4 v = make_float4(0.f, 0.f, 0.f, 0.f);
      if (gq < N_) v = *(const float4*)&qb[((size_t)bh * N_ + gq) * HD_ + 4 * c];
      v.x *= 0.125f; v.y *= 0.125f; v.z *= 0.125f; v.w *= 0.125f;
      *(float4*)&Qs[r][4 * c] = v;
    }
  }
  float l[NT_][4][8];
#pragma unroll
  for (int tt = 0; tt < NT_; tt++)
#pragma unroll
    for (int i = 0; i < 4; i++)
#pragma unroll
      for (int j = 0; j < 8; j++) l[tt][i][j] = 0.f;

#pragma unroll
  for (int tt = 0; tt < NT_; tt++) {
    const int n0 = tt * 128;
    __syncthreads();
    {
      const int c = t & 15, r0 = t >> 4;
#pragma unroll
      for (int s = 0; s < 8; s++) {
        int r = r0 + 16 * s;
        int gn = n0 + r;
        float4 v = make_float4(0.f, 0.f, 0.f, 0.f);
        if (gn < N_) v = *(const float4*)&kb[((size_t)bh * N_ + gn) * HD_ + 4 * c];
        *(float4*)&Ksf[r][4 * c] = v;
      }
    }
    __syncthreads();
#pragma unroll 2
    for (int d4 = 0; d4 < 16; d4++) {
      float4 a4[4], b4[8];
#pragma unroll
      for (int i = 0; i < 4; i++) a4[i] = *(const float4*)&Qs[tx + 16 * i][4 * d4];
#pragma unroll
      for (int j = 0; j < 8; j++) b4[j] = *(const float4*)&Ksf[ty + 16 * j][4 * d4];
#pragma unroll
      for (int i = 0; i < 4; i++)
#pragma unroll
        for (int j = 0; j < 8; j++) fma4(a4[i], b4[j], l[tt][i][j]);
    }
  }
  __syncthreads();
  // ---- row max (valid cols only)
  float* Mred = &Ksf[0][0];           // overlay: 64x16
  float* Sred = &Ksf[0][0] + 1024;
#pragma unroll
  for (int i = 0; i < 4; i++) {
    float mx = -INFINITY;
#pragma unroll
    for (int tt = 0; tt < NT_; tt++)
#pragma unroll
      for (int j = 0; j < 8; j++) {
        int col = tt * 128 + ty + 16 * j;
        if (col < N_) mx = fmaxf(mx, l[tt][i][j]);
      }
    Mred[(tx + 16 * i) * 16 + ty] = mx;
  }
  __syncthreads();
  if (t < 64) {
    float M = -INFINITY;
    for (int k = 0; k < 16; k++) M = fmaxf(M, Mred[t * 16 + k]);
    Mrow[t] = M;
    if (q0 + t < N_) rowmax_g[(size_t)bh * N_ + q0 + t] = M;
  }
  __syncthreads();
  // ---- row sum with final max
  float Mi_[4];
#pragma unroll
  for (int i = 0; i < 4; i++) Mi_[i] = Mrow[tx + 16 * i];
#pragma unroll
  for (int i = 0; i < 4; i++) {
    float s = 0.f;
#pragma unroll
    for (int tt = 0; tt < NT_; tt++)
#pragma unroll
      for (int j = 0; j < 8; j++) {
        int col = tt * 128 + ty + 16 * j;
        if (col < N_) s += expf(l[tt][i][j] - Mi_[i]);
      }
    Sred[(tx + 16 * i) * 16 + ty] = s;
  }
  __syncthreads();
  if (t < 64) {
    float S = 0.f;
    for (int k = 0; k < 16; k++) S += Sred[t * 16 + k];
    Srow[t] = S;
    if (q0 + t < N_) rowsum_g[(size_t)bh * N_ + q0 + t] = S;
  }
  __syncthreads();
  // ---- bin the register-held logits (ballot-coalesced LDS atomics)
  float inv[4];
#pragma unroll
  for (int i = 0; i < 4; i++) inv[i] = 1.f / Srow[tx + 16 * i];
#pragma unroll
  for (int tt = 0; tt < NT_; tt++) {
#pragma unroll
    for (int i = 0; i < 4; i++) {
      int gq = q0 + tx + 16 * i;
#pragma unroll
      for (int j = 0; j < 8; j++) {
        int col = tt * 128 + ty + 16 * j;
        bool valid = (gq < N_) && (col < N_);
        unsigned bin = 0xFFFFu;
        if (valid) {
          float e = expf(l[tt][i][j] - Mi_[i]);
          float v = e * inv[i];
          bin = __float_as_uint(v) >> 20;
          if (col == gq) ldiag[(size_t)bh * N_ + gq] = l[tt][i][j];
        }
        unsigned lead = (unsigned)__builtin_amdgcn_readfirstlane((int)bin);
        unsigned long long mm = __ballot(bin == lead);
        if (bin == lead) {
          if (lead != 0xFFFFu && (t & 63) == (__ffsll((unsigned long long)mm) - 1))
            atomicAdd(&hloc[lead], (unsigned)__popcll(mm));
        } else if (bin != 0xFFFFu) {
          atomicAdd(&hloc[bin], 1u);
        }
      }
    }
  }
  __syncthreads();
  for (int i = t; i < 4096; i += 256)
    if (hloc[i]) atomicAdd(&hist1[(size_t)bh * 4096 + i], hloc[i]);
}

// ------------------------------------------------------ radix-select L1
__global__ __launch_bounds__(64) void select_level(
    const unsigned* __restrict__ hist, int nbins,
    const unsigned* __restrict__ krem_in, const unsigned* __restrict__ pfx_in,
    unsigned* __restrict__ krem_out, unsigned* __restrict__ pfx_out, int shift) {
  const int bh = blockIdx.x;
  const int l = threadIdx.x;
  const int seg = nbins / 64;
  const unsigned krem = krem_in ? krem_in[bh] : KIDX_;
  const unsigned* hb = hist + (size_t)bh * nbins;
  __shared__ unsigned ps[64];
  unsigned psum = 0;
  int hi = nbins - 1 - l * seg;
  for (int i = 0; i < seg; i++) psum += hb[hi - i];
  ps[l] = psum;
  __syncthreads();
  if (l == 0) {
    unsigned cum = 0, before = 0;
    int bin = 0;
    for (int j = 0; j < 64; j++) {
      if (cum + ps[j] > krem) {
        unsigned c = cum;
        int hj = nbins - 1 - j * seg;
        for (int i = 0; i < seg; i++) {
          unsigned cnt = hb[hj - i];
          if (c + cnt > krem) { bin = hj - i; before = c; break; }
          c += cnt;
        }
        break;
      }
      cum += ps[j];
    }
    unsigned p = pfx_in ? pfx_in[bh] : 0u;
    pfx_out[bh] = (p << shift) | (unsigned)bin;
    krem_out[bh] = krem - before;
  }
}

// ------------------------- pass B: candidate collection + hist2 fallback
// QK recompute; elements whose top-12 bits match pfx1 are appended to a
// compact per-bh buffer (wave-aggregated atomics) and binned into hist2
// (bits[19:8]) for the overflow fallback.
__global__ __launch_bounds__(256) void cand_pass(
    const float* __restrict__ qb, const float* __restrict__ kb,
    const float* __restrict__ rowmax_g, const float* __restrict__ rowsum_g,
    const unsigned* __restrict__ pfx1, unsigned* __restrict__ candCnt,
    unsigned* __restrict__ cand, int cap, unsigned* __restrict__ hist2) {
  __shared__ __align__(16) float Qs[64][68];
  __shared__ __align__(16) float Ksf[128][68];
  __shared__ unsigned hloc[4096];
  const int bh = blockIdx.x;
  const int q0 = blockIdx.y * 64;
  const int t = threadIdx.x;
  const int tx = t & 15, ty = t >> 4;
  for (int i = t; i < 4096; i += 256) hloc[i] = 0u;
  const unsigned pf = pfx1[bh];
  {
    const int c = t & 15, r0 = t >> 4;
#pragma unroll
    for (int s = 0; s < 4; s++) {
      int r = r0 + 16 * s;
      int gq = q0 + r;
      float4 v = make_float4(0.f, 0.f, 0.f, 0.f);
      if (gq < N_) v = *(const float4*)&qb[((size_t)bh * N_ + gq) * HD_ + 4 * c];
      v.x *= 0.125f; v.y *= 0.125f; v.z *= 0.125f; v.w *= 0.125f;
      *(float4*)&Qs[r][4 * c] = v;
    }
  }
  float M[4], inv[4];
#pragma unroll
  for (int i = 0; i < 4; i++) {
    int gq = q0 + tx + 16 * i;
    if (gq < N_) {
      M[i] = rowmax_g[(size_t)bh * N_ + gq];
      inv[i] = 1.f / rowsum_g[(size_t)bh * N_ + gq];
    } else { M[i] = 0.f; inv[i] = 0.f; }
  }
  for (int n0 = 0; n0 < N_; n0 += 128) {
    __syncthreads();
    {
      const int c = t & 15, r0 = t >> 4;
#pragma unroll
      for (int s = 0; s < 8; s++) {
        int r = r0 + 16 * s;
        int gn = n0 + r;
        float4 v = make_float4(0.f, 0.f, 0.f, 0.f);
        if (gn < N_) v = *(const float4*)&kb[((size_t)bh * N_ + gn) * HD_ + 4 * c];
        *(float4*)&Ksf[r][4 * c] = v;
      }
    }
    __syncthreads();
    float l[4][8];
#pragma unroll
    for (int i = 0; i < 4; i++)
#pragma unroll
      for (int j = 0; j < 8; j++) l[i][j] = 0.f;
#pragma unroll 2
    for (int d4 = 0; d4 < 16; d4++) {
      float4 a4[4], b4[8];
#pragma unroll
      for (int i = 0; i < 4; i++) a4[i] = *(const float4*)&Qs[tx + 16 * i][4 * d4];
#pragma unroll
      for (int j = 0; j < 8; j++) b4[j] = *(const float4*)&Ksf[ty + 16 * j][4 * d4];
#pragma unroll
      for (int i = 0; i < 4; i++)
#pragma unroll
        for (int j = 0; j < 8; j++) fma4(a4[i], b4[j], l[i][j]);
    }
#pragma unroll
    for (int i = 0; i < 4; i++) {
      int gq = q0 + tx + 16 * i;
#pragma unroll
      for (int j = 0; j < 8; j++) {
        bool valid = (gq < N_) && (n0 + ty + 16 * j < N_);
        unsigned bits = 0u;
        bool match = false;
        if (valid) {
          float e = expf(l[i][j] - M[i]);
          float v = e * inv[i];
          bits = __float_as_uint(v);
          match = ((bits >> 20) == pf);
        }
        unsigned long long mm = __ballot(match);
        if (mm) {
          int leader = __ffsll((unsigned long long)mm) - 1;
          unsigned base = 0;
          if ((t & 63) == leader)
            base = atomicAdd(&candCnt[bh], (unsigned)__popcll(mm));
          base = (unsigned)__shfl((int)base, leader, 64);
          if (match) {
            unsigned rank = (unsigned)__popcll(mm & ((1ull << (t & 63)) - 1ull));
            unsigned idx = base + rank;
            if ((int)idx < cap) cand[(size_t)bh * CAPMAX_ + idx] = bits;
            atomicAdd(&hloc[(bits >> 8) & 0xFFFu], 1u);
          }
        }
      }
    }
  }
  __syncthreads();
  for (int i = t; i < 4096; i += 256)
    if (hloc[i]) atomicAdd(&hist2[(size_t)bh * 4096 + i], hloc[i]);
}

// -------------------- select_mid: finish sigma from candidates (or flag)
__global__ __launch_bounds__(256) void select_mid(
    const unsigned* __restrict__ cand, const unsigned* __restrict__ candCnt,
    int cap, const unsigned* __restrict__ krem1, const unsigned* __restrict__ pfx1,
    const unsigned* __restrict__ hist2, unsigned* __restrict__ krem2,
    unsigned* __restrict__ pfx2, unsigned* __restrict__ sigbits,
    unsigned* __restrict__ flag) {
  const int bh = blockIdx.x;
  const int t = threadIdx.x;
  __shared__ unsigned h[4096];
  __shared__ unsigned ps[256];
  __shared__ unsigned sh_bin, sh_krem;
  const unsigned cnt = candCnt[bh];
  const unsigned krem = krem1[bh];
  const unsigned p1 = pfx1[bh];
  if (cap > 0 && cnt <= (unsigned)cap) {
    const unsigned* cb = cand + (size_t)bh * CAPMAX_;
    // level A: bits[19:10]
    for (int i = t; i < 1024; i += 256) h[i] = 0u;
    __syncthreads();
    for (unsigned i = t; i < cnt; i += 256) atomicAdd(&h[(cb[i] >> 10) & 1023u], 1u);
    __syncthreads();
    { unsigned s = 0; int hi = 1023 - t * 4;
      for (int k = 0; k < 4; k++) s += h[hi - k];
      ps[t] = s; }
    __syncthreads();
    if (t == 0) {
      unsigned cum = 0, before = 0; int bin = 0;
      for (int j = 0; j < 256; j++) {
        unsigned pj = ps[j];
        if (cum + pj > krem) {
          unsigned c = cum; int hj = 1023 - j * 4;
          for (int k = 0; k < 4; k++) {
            unsigned cc = h[hj - k];
            if (c + cc > krem) { bin = hj - k; before = c; break; }
            c += cc;
          }
          break;
        }
        cum += pj;
      }
      sh_bin = (unsigned)bin; sh_krem = krem - before;
    }
    __syncthreads();
    const unsigned binA = sh_bin;
    const unsigned kremA = sh_krem;
    __syncthreads();
    // level B: bits[9:0]
    for (int i = t; i < 1024; i += 256) h[i] = 0u;
    __syncthreads();
    for (unsigned i = t; i < cnt; i += 256) {
      unsigned c = cb[i];
      if (((c >> 10) & 1023u) == binA) atomicAdd(&h[c & 1023u], 1u);
    }
    __syncthreads();
    { unsigned s = 0; int hi = 1023 - t * 4;
      for (int k = 0; k < 4; k++) s += h[hi - k];
      ps[t] = s; }
    __syncthreads();
    if (t == 0) {
      unsigned cum = 0; int bin = 0;
      for (int j = 0; j < 256; j++) {
        unsigned pj = ps[j];
        if (cum + pj > kremA) {
          unsigned c = cum; int hj = 1023 - j * 4;
          for (int k = 0; k < 4; k++) {
            unsigned cc = h[hj - k];
            if (c + cc > kremA) { bin = hj - k; break; }
            c += cc;
          }
          break;
        }
        cum += pj;
      }
      sigbits[bh] = (p1 << 20) | (binA << 10) | (unsigned)bin;
      flag[bh] = 0u;
    }
  } else {
    // overflow fallback: select 12 bins of bits[19:8] from hist2
    const unsigned* hb = hist2 + (size_t)bh * 4096;
    { unsigned s = 0; int hi = 4095 - t * 16;
      for (int k = 0; k < 16; k++) s += hb[hi - k];
      ps[t] = s; }
    __syncthreads();
    if (t == 0) {
      unsigned cum = 0, before = 0; int bin = 0;
      for (int j = 0; j < 256; j++) {
        unsigned pj = ps[j];
        if (cum + pj > krem) {
          unsigned c = cum; int hj = 4095 - j * 16;
          for (int k = 0; k < 16; k++) {
            unsigned cc = hb[hj - k];
            if (c + cc > krem) { bin = hj - k; before = c; break; }
            c += cc;
          }
          break;
        }
        cum += pj;
      }
      pfx2[bh] = (p1 << 12) | (unsigned)bin;
      krem2[bh] = krem - before;
      flag[bh] = 1u;
    }
  }
}

// -------------------- flag-gated L3 pass (overflow fallback only)
__global__ __launch_bounds__(256) void hist_l3(
    const float* __restrict__ qb, const float* __restrict__ kb,
    const float* __restrict__ rowmax_g, const float* __restrict__ rowsum_g,
    const unsigned* __restrict__ pfx2, const unsigned* __restrict__ flag,
    unsigned* __restrict__ hist3) {
  const int bh = blockIdx.x;
  if (flag[bh] == 0u) return;
  __shared__ __align__(16) float Qs[64][68];
  __shared__ __align__(16) float Ksf[128][68];
  __shared__ unsigned hloc[256];
  const int q0 = blockIdx.y * 64;
  const int t = threadIdx.x;
  const int tx = t & 15, ty = t >> 4;
  if (t < 256) hloc[t] = 0u;
  const unsigned pf = pfx2[bh];
  {
    const int c = t & 15, r0 = t >> 4;
#pragma unroll
    for (int s = 0; s < 4; s++) {
      int r = r0 + 16 * s;
      int gq = q0 + r;
      float4 v = make_float4(0.f, 0.f, 0.f, 0.f);
      if (gq < N_) v = *(const float4*)&qb[((size_t)bh * N_ + gq) * HD_ + 4 * c];
      v.x *= 0.125f; v.y *= 0.125f; v.z *= 0.125f; v.w *= 0.125f;
      *(float4*)&Qs[r][4 * c] = v;
    }
  }
  float M[4], inv[4];
#pragma unroll
  for (int i = 0; i < 4; i++) {
    int gq = q0 + tx + 16 * i;
    if (gq < N_) {
      M[i] = rowmax_g[(size_t)bh * N_ + gq];
      inv[i] = 1.f / rowsum_g[(size_t)bh * N_ + gq];
    } else { M[i] = 0.f; inv[i] = 0.f; }
  }
  for (int n0 = 0; n0 < N_; n0 += 128) {
    __syncthreads();
    {
      const int c = t & 15, r0 = t >> 4;
#pragma unroll
      for (int s = 0; s < 8; s++) {
        int r = r0 + 16 * s;
        int gn = n0 + r;
        float4 v = make_float4(0.f, 0.f, 0.f, 0.f);
        if (gn < N_) v = *(const float4*)&kb[((size_t)bh * N_ + gn) * HD_ + 4 * c];
        *(float4*)&Ksf[r][4 * c] = v;
      }
    }
    __syncthreads();
    float l[4][8];
#pragma unroll
    for (int i = 0; i < 4; i++)
#pragma unroll
      for (int j = 0; j < 8; j++) l[i][j] = 0.f;
#pragma unroll 2
    for (int d4 = 0; d4 < 16; d4++) {
      float4 a4[4], b4[8];
#pragma unroll
      for (int i = 0; i < 4; i++) a4[i] = *(const float4*)&Qs[tx + 16 * i][4 * d4];
#pragma unroll
      for (int j = 0; j < 8; j++) b4[j] = *(const float4*)&Ksf[ty + 16 * j][4 * d4];
#pragma unroll
      for (int i = 0; i < 4; i++)
#pragma unroll
        for (int j = 0; j < 8; j++) fma4(a4[i], b4[j], l[i][j]);
    }
#pragma unroll
    for (int i = 0; i < 4; i++) {
      int gq = q0 + tx + 16 * i;
#pragma unroll
      for (int j = 0; j < 8; j++) {
        if ((gq < N_) && (n0 + ty + 16 * j < N_)) {
          float e = expf(l[i][j] - M[i]);
          float v = e * inv[i];
          unsigned bits = __float_as_uint(v);
          if ((bits >> 8) == pf) atomicAdd(&hloc[bits & 0xFFu], 1u);
        }
      }
    }
  }
  __syncthreads();
  if (t < 256 && hloc[t]) atomicAdd(&hist3[(size_t)bh * 256 + t], hloc[t]);
}

__global__ __launch_bounds__(64) void select_l3(
    const unsigned* __restrict__ hist3, const unsigned* __restrict__ krem2,
    const unsigned* __restrict__ pfx2, const unsigned* __restrict__ flag,
    unsigned* __restrict__ sigbits) {
  const int bh = blockIdx.x;
  if (flag[bh] == 0u) return;
  const int l = threadIdx.x;
  const unsigned krem = krem2[bh];
  const unsigned* hb = hist3 + (size_t)bh * 256;
  __shared__ unsigned ps[64];
  unsigned psum = 0;
  int hi = 255 - l * 4;
  for (int i = 0; i < 4; i++) psum += hb[hi - i];
  ps[l] = psum;
  __syncthreads();
  if (l == 0) {
    unsigned cum = 0; int bin = 0;
    for (int j = 0; j < 64; j++) {
      if (cum + ps[j] > krem) {
        unsigned c = cum; int hj = 255 - j * 4;
        for (int i = 0; i < 4; i++) {
          unsigned cnt = hb[hj - i];
          if (c + cnt > krem) { bin = hj - i; break; }
          c += cnt;
        }
        break;
      }
      cum += ps[j];
    }
    sigbits[bh] = (pfx2[bh] << 8) | (unsigned)bin;
  }
}

// ------------------------------------------------- token ranking (stable)
__global__ __launch_bounds__(576) void rank_kernel(
    const float* __restrict__ ldiag, const float* __restrict__ rowmax_g,
    const float* __restrict__ rowsum_g, const unsigned* __restrict__ sigbits,
    int* __restrict__ kept) {
  const int b = blockIdx.x;
  const int i = threadIdx.x;  // token i+1
  __shared__ float sc[576];
  float s = 0.f;
  for (int h = 0; h < H_; h++) {
    int bh = b * H_ + h;
    float l = ldiag[(size_t)bh * N_ + (i + 1)];
    float M = rowmax_g[(size_t)bh * N_ + (i + 1)];
    float inv = 1.f / rowsum_g[(size_t)bh * N_ + (i + 1)];
    float e = expf(l - M);
    float v = e * inv;   // bit-identical to hist/AV computation
    float sg = __uint_as_float(sigbits[bh]);
    if (v >= sg) s = fmaxf(s, v);
  }
  sc[i] = s;
  __syncthreads();
  int r = 0;
  for (int j = 0; j < 576; j++) {
    float sj = sc[j];
    if (sj > s || (sj == s && j < i)) r++;
  }
  if (r < KK_ - 1) kept[b * KK_ + r + 1] = i + 1;
  if (i == 0) kept[b * KK_] = 0;
}

// ------------------------------------------------------ gather x_original
__global__ __launch_bounds__(256) void gather_x(
    const float* __restrict__ xo, const int* __restrict__ kept,
    float* __restrict__ out2) {
  const int bp = blockIdx.x;
  const int b = bp / KK_, p = bp % KK_;
  const int src = kept[b * KK_ + p];
  const float* s = xo + ((size_t)b * N_ + src) * C_;
  float* d = out2 + (size_t)bp * C_;
  for (int c = threadIdx.x; c < C_; c += 256) d[c] = s[c];
}

// ------------------------------------------- AV (QK recompute + PV)
__global__ __launch_bounds__(256) void av_kernel(
    const float* __restrict__ qb, const float* __restrict__ kb,
    const float* __restrict__ vb, const int* __restrict__ kept,
    const float* __restrict__ rowmax_g, const float* __restrict__ rowsum_g,
    const unsigned* __restrict__ sigbits, float* __restrict__ out1) {
  __shared__ __align__(16) float Qs[64][68];
  __shared__ __align__(16) float Ksf[64][68];   // K, then P overlay
  __shared__ __align__(16) float Vs[64][68];
  __shared__ int ridx[64];
  __shared__ float Ml[64], Il[64];
  const int bh = blockIdx.x;
  const int p0 = blockIdx.y * 64;
  const int b = bh / H_, h = bh % H_;
  const float sigma = __uint_as_float(sigbits[bh]);
  const int t = threadIdx.x;
  const int tx = t & 15, ty = t >> 4;
  if (t < 64) {
    int pp = p0 + t;
    int r = (pp < KK_) ? kept[b * KK_ + pp] : 0;
    ridx[t] = r;
    Ml[t] = rowmax_g[(size_t)bh * N_ + r];
    Il[t] = 1.f / rowsum_g[(size_t)bh * N_ + r];
  }
  __syncthreads();
  {
    const int c = t & 15, r0 = t >> 4;
#pragma unroll
    for (int s = 0; s < 4; s++) {
      int r = r0 + 16 * s;
      int gq = ridx[r];
      float4 v = *(const float4*)&qb[((size_t)bh * N_ + gq) * HD_ + 4 * c];
      v.x *= 0.125f; v.y *= 0.125f; v.z *= 0.125f; v.w *= 0.125f;
      *(float4*)&Qs[r][4 * c] = v;
    }
  }
  float M[4], inv[4];
#pragma unroll
  for (int i = 0; i < 4; i++) { int row = tx + 16 * i; M[i] = Ml[row]; inv[i] = Il[row]; }
  float acc[4][4] = {};
  for (int n0 = 0; n0 < N_; n0 += 64) {
    __syncthreads();
    {
      const int c = t & 15, r0 = t >> 4;
#pragma unroll
      for (int s = 0; s < 4; s++) {
        int r = r0 + 16 * s;
        int gn = n0 + r;
        float4 kv = make_float4(0.f, 0.f, 0.f, 0.f);
        float4 vv = make_float4(0.f, 0.f, 0.f, 0.f);
        if (gn < N_) {
          kv = *(const float4*)&kb[((size_t)bh * N_ + gn) * HD_ + 4 * c];
          vv = *(const float4*)&vb[((size_t)bh * N_ + gn) * HD_ + 4 * c];
        }
        *(float4*)&Ksf[r][4 * c] = kv;
        *(float4*)&Vs[r][4 * c] = vv;
      }
    }
    __syncthreads();
    float l[4][4];
#pragma unroll
    for (int i = 0; i < 4; i++)
#pragma unroll
      for (int j = 0; j < 4; j++) l[i][j] = 0.f;
#pragma unroll 4
    for (int d4 = 0; d4 < 16; d4++) {
      float4 a4[4], b4[4];
#pragma unroll
      for (int i = 0; i < 4; i++) a4[i] = *(const float4*)&Qs[tx + 16 * i][4 * d4];
#pragma unroll
      for (int j = 0; j < 4; j++) b4[j] = *(const float4*)&Ksf[4 * ty + j][4 * d4];
#pragma unroll
      for (int i = 0; i < 4; i++)
#pragma unroll
        for (int j = 0; j < 4; j++) fma4(a4[i], b4[j], l[i][j]);
    }
    __syncthreads();   // QK done -> overlay P on Ksf
#pragma unroll
    for (int i = 0; i < 4; i++) {
      float4 pv4;
      float* pp = (float*)&pv4;
#pragma unroll
      for (int j = 0; j < 4; j++) {
        float e = expf(l[i][j] - M[i]);
        float v = e * inv[i];
        pp[j] = (v >= sigma) ? v : 0.f;   // padded cols harmless: V=0
      }
      *(float4*)&Ksf[tx + 16 * i][4 * ty] = pv4;
    }
    __syncthreads();
#pragma unroll 4
    for (int nb = 0; nb < 16; nb++) {
      float4 pa4[4];
#pragma unroll
      for (int i = 0; i < 4; i++) pa4[i] = *(const float4*)&Ksf[tx + 16 * i][4 * nb];
#pragma unroll
      for (int e = 0; e < 4; e++) {
        float4 vv4 = *(const float4*)&Vs[4 * nb + e][4 * ty];
#pragma unroll
        for (int i = 0; i < 4; i++) {
          float pvv = ((const float*)&pa4[i])[e];
          acc[i][0] = __builtin_fmaf(pvv, vv4.x, acc[i][0]);
          acc[i][1] = __builtin_fmaf(pvv, vv4.y, acc[i][1]);
          acc[i][2] = __builtin_fmaf(pvv, vv4.z, acc[i][2]);
          acc[i][3] = __builtin_fmaf(pvv, vv4.w, acc[i][3]);
        }
      }
    }
  }
#pragma unroll
  for (int i = 0; i < 4; i++) {
    int pp = p0 + tx + 16 * i;
    if (pp >= KK_) continue;
    float4 o = make_float4(acc[i][0], acc[i][1], acc[i][2], acc[i][3]);
    *(float4*)&out1[((size_t)(b * KK_ + pp)) * C_ + h * HD_ + 4 * ty] = o;
  }
}

// ------------------------------------------------------------ proj GEMM
__global__ __launch_bounds__(256) void proj_gemm(
    const float* __restrict__ Xi, const float* __restrict__ W,
    const float* __restrict__ bias, float* __restrict__ out) {
  __shared__ __align__(16) float Xs[128][36];
  __shared__ __align__(16) float Ws2[128][36];
  const int m0 = blockIdx.x * 128;
  const int n0 = blockIdx.y * 128;
  const int t = threadIdx.x;
  const int tx = t & 15, ty = t >> 4;
  float acc[8][8] = {};
  for (int k0 = 0; k0 < 768; k0 += 32) {
    __syncthreads();
    {
      const int c = t & 7, r0 = t >> 3;
#pragma unroll
      for (int s = 0; s < 4; s++) {
        int r = r0 + 32 * s;
        float4 v = *(const float4*)&Xi[(size_t)(m0 + r) * 768 + k0 + 4 * c];
        *(float4*)&Xs[r][4 * c] = v;
        float4 w = *(const float4*)&W[(size_t)(n0 + r) * 768 + k0 + 4 * c];
        *(float4*)&Ws2[r][4 * c] = w;
      }
    }
    __syncthreads();
#pragma unroll
    for (int d4 = 0; d4 < 8; d4++) {
      float4 a4[8], b4[8];
#pragma unroll
      for (int i = 0; i < 8; i++) a4[i] = *(const float4*)&Xs[tx + 16 * i][4 * d4];
#pragma unroll
      for (int j = 0; j < 8; j++) b4[j] = *(const float4*)&Ws2[ty + 16 * j][4 * d4];
#pragma unroll
      for (int i = 0; i < 8; i++)
#pragma unroll
        for (int j = 0; j < 8; j++) fma4(a4[i], b4[j], acc[i][j]);
    }
  }
  for (int i = 0; i < 8; i++) {
    int gm = m0 + tx + 16 * i;   // M2 = 8320 = 65*128, no guard
    for (int j = 0; j < 8; j++) {
      int gn = n0 + ty + 16 * j;
      out[(size_t)gm * C_ + gn] = acc[i][j] + bias[gn];
    }
  }
}

// ---------------------------------------------------------------- launcher
extern "C" void kernel_launch(void* const* d_in, const int* in_sizes, int n_in,
                              void* d_out, int out_size, void* d_ws, size_t ws_size,
                              hipStream_t stream) {
  (void)in_sizes; (void)n_in; (void)out_size;
  const float* x    = (const float*)d_in[0];
  const float* xo   = (const float*)d_in[1];
  const float* qkvw = (const float*)d_in[2];
  const float* pw   = (const float*)d_in[3];
  const float* pb   = (const float*)d_in[4];

  char* ws = (char*)d_ws;
  size_t off = 0;
  auto alloc = [&](size_t bytes) -> char* {
    char* p = ws + off;
    off += (bytes + 255) & ~(size_t)255;
    return p;
  };
  const size_t szQ    = (size_t)BH_ * N_ * HD_ * 4;   // 28.4 MB
  const size_t szOut1 = (size_t)M2_ * C_ * 4;         // 25.6 MB
  const size_t szRow  = (size_t)BH_ * N_ * 4;         // 443 KB
  const size_t szH12  = (size_t)BH_ * 4096 * 4;       // 3.1 MB
  const size_t szH3   = (size_t)BH_ * 256 * 4;

  float* qb     = (float*)alloc(szQ);
  float* kb     = (float*)alloc(szQ);
  float* vb     = (float*)alloc(szQ);
  float* out1   = (float*)alloc(szOut1);
  float* ldiag  = (float*)alloc(szRow);
  float* rowmax = (float*)alloc(szRow);
  float* rowsum = (float*)alloc(szRow);
  unsigned* hist1 = (unsigned*)alloc(szH12);
  unsigned* hist2 = (unsigned*)alloc(szH12);
  unsigned* hist3 = (unsigned*)alloc(szH3);
  unsigned* pfx1  = (unsigned*)alloc(BH_ * 4);
  unsigned* krem1 = (unsigned*)alloc(BH_ * 4);
  unsigned* pfx2  = (unsigned*)alloc(BH_ * 4);
  unsigned* krem2 = (unsigned*)alloc(BH_ * 4);
  unsigned* sigb  = (unsigned*)alloc(BH_ * 4);
  unsigned* flag  = (unsigned*)alloc(BH_ * 4);
  unsigned* candCnt = (unsigned*)alloc(BH_ * 4);
  int* kept       = (int*)alloc((size_t)B_ * KK_ * 4);
  // candidate buffer last: only used if workspace is large enough
  size_t off_nocand = off;
  unsigned* cand  = (unsigned*)alloc((size_t)BH_ * CAPMAX_ * 4);
  const int cap = (ws_size >= off) ? CAPMAX_ : 0;
  if (cap == 0) cand = (unsigned*)(ws + off_nocand - 256);  // never dereferenced

  hipMemsetAsync(hist1, 0, szH12, stream);
  hipMemsetAsync(hist2, 0, szH12, stream);
  hipMemsetAsync(hist3, 0, szH3, stream);
  hipMemsetAsync(candCnt, 0, BH_ * 4, stream);

  qkv_gemm<<<dim3(73, 18), 256, 0, stream>>>(x, qkvw, qb, kb, vb);
  stats_hist1<<<dim3(BH_, 10), 256, 0, stream>>>(qb, kb, rowmax, rowsum, ldiag, hist1);
  select_level<<<BH_, 64, 0, stream>>>(hist1, 4096, nullptr, nullptr, krem1, pfx1, 12);
  cand_pass<<<dim3(BH_, 10), 256, 0, stream>>>(qb, kb, rowmax, rowsum, pfx1,
                                               candCnt, cand, cap, hist2);
  select_mid<<<BH_, 256, 0, stream>>>(cand, candCnt, cap, krem1, pfx1, hist2,
                                      krem2, pfx2, sigb, flag);
  hist_l3<<<dim3(BH_, 10), 256, 0, stream>>>(qb, kb, rowmax, rowsum, pfx2, flag, hist3);
  select_l3<<<BH_, 64, 0, stream>>>(hist3, krem2, pfx2, flag, sigb);
  rank_kernel<<<B_, 576, 0, stream>>>(ldiag, rowmax, rowsum, sigb, kept);

  float* outp = (float*)d_out;
  gather_x<<<M2_, 256, 0, stream>>>(xo, kept, outp + (size_t)M2_ * C_);
  av_kernel<<<dim3(BH_, 9), 256, 0, stream>>>(qb, kb, vb, kept, rowmax, rowsum, sigb, out1);
  proj_gemm<<<dim3(65, 6), 256, 0, stream>>>(out1, pw, pb, outp);
}

// Round 6
// 2188.509 us; speedup vs baseline: 1.6492x; 1.6492x over previous
//
#include <hip/hip_runtime.h>
#include <cstdint>
#include <cstddef>

// Attention_41231686042092: ViT attention + softmax sparsification (per-(b,h)
// exact median threshold via 3-level radix select on f32 bit patterns) +
// diag-based token pruning + projection. All f32 (ranking needs exact-index
// fidelity; bf16 noise would flip argsort order).
//
// Round-6: round-4's proven 12/12/8 radix-select flow (LDS-atomic histograms
// only — round-5's global-atomic candidate compaction serialized, reverted)
// + round-5's wins: 8x8-microtile qkv/proj GEMMs and fused stats+hist1.
// Every logit is a single ascending-k fmaf chain (fma4) -> bit-identical
// across all passes; M/S loaded from the same globals everywhere.

namespace {
constexpr int B_  = 16;
constexpr int N_  = 577;
constexpr int C_  = 768;
constexpr int H_  = 12;
constexpr int HD_ = 64;
constexpr int BH_ = B_ * H_;            // 192
constexpr int KK_ = N_ - 57;            // 520 kept tokens
constexpr unsigned KIDX_ = 166464u;     // int(N*N*0.5), 0-based desc rank
constexpr int M1_ = B_ * N_;            // 9232
constexpr int M2_ = B_ * KK_;           // 8320
constexpr int NT_ = 5;                  // col tiles of 128 covering 577
}

__device__ __forceinline__ void fma4(const float4& a, const float4& b, float& acc) {
  acc = __builtin_fmaf(a.x, b.x, acc);
  acc = __builtin_fmaf(a.y, b.y, acc);
  acc = __builtin_fmaf(a.z, b.z, acc);
  acc = __builtin_fmaf(a.w, b.w, acc);
}

// ---------------------------------------------------------------- QKV GEMM
// Y = X @ W^T ; X:[M1,768], W:[2304,768]. 128x128 tile, 8x8 microtile, BK=32.
__global__ __launch_bounds__(256) void qkv_gemm(
    const float* __restrict__ X, const float* __restrict__ W,
    float* __restrict__ qb, float* __restrict__ kb, float* __restrict__ vb) {
  __shared__ __align__(16) float Xs[128][36];
  __shared__ __align__(16) float Ws2[128][36];
  const int m0 = blockIdx.x * 128;
  const int n0 = blockIdx.y * 128;
  const int t = threadIdx.x;
  const int tx = t & 15, ty = t >> 4;
  float acc[8][8] = {};
  for (int k0 = 0; k0 < 768; k0 += 32) {
    __syncthreads();
    {
      const int c = t & 7, r0 = t >> 3;  // 8 float4-cols, 32 rows per pass
#pragma unroll
      for (int s = 0; s < 4; s++) {
        int r = r0 + 32 * s;
        int gm = m0 + r;
        float4 v = make_float4(0.f, 0.f, 0.f, 0.f);
        if (gm < M1_) v = *(const float4*)&X[(size_t)gm * 768 + k0 + 4 * c];
        *(float4*)&Xs[r][4 * c] = v;
        float4 w = *(const float4*)&W[(size_t)(n0 + r) * 768 + k0 + 4 * c];
        *(float4*)&Ws2[r][4 * c] = w;
      }
    }
    __syncthreads();
#pragma unroll
    for (int d4 = 0; d4 < 8; d4++) {
      float4 a4[8], b4[8];
#pragma unroll
      for (int i = 0; i < 8; i++) a4[i] = *(const float4*)&Xs[tx + 16 * i][4 * d4];
#pragma unroll
      for (int j = 0; j < 8; j++) b4[j] = *(const float4*)&Ws2[ty + 16 * j][4 * d4];
#pragma unroll
      for (int i = 0; i < 8; i++)
#pragma unroll
        for (int j = 0; j < 8; j++) fma4(a4[i], b4[j], acc[i][j]);
    }
  }
  for (int i = 0; i < 8; i++) {
    int gm = m0 + tx + 16 * i;
    if (gm >= M1_) continue;
    int b = gm / N_, n = gm % N_;
    for (int j = 0; j < 8; j++) {
      int gn = n0 + ty + 16 * j;
      int which = gn / C_, rem = gn % C_;
      int h = rem >> 6, d = rem & 63;
      float* dst = (which == 0) ? qb : (which == 1) ? kb : vb;
      dst[(((size_t)(b * H_ + h)) * N_ + n) * HD_ + d] = acc[i][j];
    }
  }
}

// ------------------------------------- pass A: stats + hist-L1 (fused)
// 64 q-rows/block x 5 col-tiles of 128; logits kept in registers
// (l[5][4][8] = 160 VGPR). Row max/sum reduced from registers, then the
// same registers are binned into the 12-bit histogram.
__global__ __launch_bounds__(256) void stats_hist1(
    const float* __restrict__ qb, const float* __restrict__ kb,
    float* __restrict__ rowmax_g, float* __restrict__ rowsum_g,
    float* __restrict__ ldiag, unsigned* __restrict__ hist1) {
  __shared__ __align__(16) float Qs[64][68];
  __shared__ __align__(16) float Ksf[128][68];
  __shared__ unsigned hloc[4096];
  __shared__ float Mrow[64], Srow[64];
  const int bh = blockIdx.x;
  const int q0 = blockIdx.y * 64;
  const int t = threadIdx.x;
  const int tx = t & 15, ty = t >> 4;
  for (int i = t; i < 4096; i += 256) hloc[i] = 0u;
  {
    const int c = t & 15, r0 = t >> 4;
#pragma unroll
    for (int s = 0; s < 4; s++) {
      int r = r0 + 16 * s;
      int gq = q0 + r;
      float4 v = make_float4(0.f, 0.f, 0.f, 0.f);
      if (gq < N_) v = *(const float4*)&qb[((size_t)bh * N_ + gq) * HD_ + 4 * c];
      v.x *= 0.125f; v.y *= 0.125f; v.z *= 0.125f; v.w *= 0.125f;
      *(float4*)&Qs[r][4 * c] = v;
    }
  }
  float l[NT_][4][8];
#pragma unroll
  for (int tt = 0; tt < NT_; tt++)
#pragma unroll
    for (int i = 0; i < 4; i++)
#pragma unroll
      for (int j = 0; j < 8; j++) l[tt][i][j] = 0.f;

#pragma unroll
  for (int tt = 0; tt < NT_; tt++) {
    const int n0 = tt * 128;
    __syncthreads();
    {
      const int c = t & 15, r0 = t >> 4;
#pragma unroll
      for (int s = 0; s < 8; s++) {
        int r = r0 + 16 * s;
        int gn = n0 + r;
        float4 v = make_float4(0.f, 0.f, 0.f, 0.f);
        if (gn < N_) v = *(const float4*)&kb[((size_t)bh * N_ + gn) * HD_ + 4 * c];
        *(float4*)&Ksf[r][4 * c] = v;
      }
    }
    __syncthreads();
#pragma unroll 2
    for (int d4 = 0; d4 < 16; d4++) {
      float4 a4[4], b4[8];
#pragma unroll
      for (int i = 0; i < 4; i++) a4[i] = *(const float4*)&Qs[tx + 16 * i][4 * d4];
#pragma unroll
      for (int j = 0; j < 8; j++) b4[j] = *(const float4*)&Ksf[ty + 16 * j][4 * d4];
#pragma unroll
      for (int i = 0; i < 4; i++)
#pragma unroll
        for (int j = 0; j < 8; j++) fma4(a4[i], b4[j], l[tt][i][j]);
    }
  }
  __syncthreads();
  // ---- row max (valid cols only)
  float* Mred = &Ksf[0][0];           // overlay: 64x16
  float* Sred = &Ksf[0][0] + 1024;
#pragma unroll
  for (int i = 0; i < 4; i++) {
    float mx = -INFINITY;
#pragma unroll
    for (int tt = 0; tt < NT_; tt++)
#pragma unroll
      for (int j = 0; j < 8; j++) {
        int col = tt * 128 + ty + 16 * j;
        if (col < N_) mx = fmaxf(mx, l[tt][i][j]);
      }
    Mred[(tx + 16 * i) * 16 + ty] = mx;
  }
  __syncthreads();
  if (t < 64) {
    float M = -INFINITY;
    for (int k = 0; k < 16; k++) M = fmaxf(M, Mred[t * 16 + k]);
    Mrow[t] = M;
    if (q0 + t < N_) rowmax_g[(size_t)bh * N_ + q0 + t] = M;
  }
  __syncthreads();
  // ---- row sum with final max
  float Mi_[4];
#pragma unroll
  for (int i = 0; i < 4; i++) Mi_[i] = Mrow[tx + 16 * i];
#pragma unroll
  for (int i = 0; i < 4; i++) {
    float s = 0.f;
#pragma unroll
    for (int tt = 0; tt < NT_; tt++)
#pragma unroll
      for (int j = 0; j < 8; j++) {
        int col = tt * 128 + ty + 16 * j;
        if (col < N_) s += expf(l[tt][i][j] - Mi_[i]);
      }
    Sred[(tx + 16 * i) * 16 + ty] = s;
  }
  __syncthreads();
  if (t < 64) {
    float S = 0.f;
    for (int k = 0; k < 16; k++) S += Sred[t * 16 + k];
    Srow[t] = S;
    if (q0 + t < N_) rowsum_g[(size_t)bh * N_ + q0 + t] = S;
  }
  __syncthreads();
  // ---- bin the register-held logits (ballot-coalesced LDS atomics)
  float inv[4];
#pragma unroll
  for (int i = 0; i < 4; i++) inv[i] = 1.f / Srow[tx + 16 * i];
#pragma unroll
  for (int tt = 0; tt < NT_; tt++) {
#pragma unroll
    for (int i = 0; i < 4; i++) {
      int gq = q0 + tx + 16 * i;
#pragma unroll
      for (int j = 0; j < 8; j++) {
        int col = tt * 128 + ty + 16 * j;
        bool valid = (gq < N_) && (col < N_);
        unsigned bin = 0xFFFFu;
        if (valid) {
          float e = expf(l[tt][i][j] - Mi_[i]);
          float v = e * inv[i];
          bin = __float_as_uint(v) >> 20;
          if (col == gq) ldiag[(size_t)bh * N_ + gq] = l[tt][i][j];
        }
        unsigned lead = (unsigned)__builtin_amdgcn_readfirstlane((int)bin);
        unsigned long long mm = __ballot(bin == lead);
        if (bin == lead) {
          if (lead != 0xFFFFu && (t & 63) == (__ffsll((unsigned long long)mm) - 1))
            atomicAdd(&hloc[lead], (unsigned)__popcll(mm));
        } else if (bin != 0xFFFFu) {
          atomicAdd(&hloc[bin], 1u);
        }
      }
    }
  }
  __syncthreads();
  for (int i = t; i < 4096; i += 256)
    if (hloc[i]) atomicAdd(&hist1[(size_t)bh * 4096 + i], hloc[i]);
}

// ----------------------------------------- histogram refine passes
// MODE 1: bits[19:8] conditioned on pfx1.  MODE 2: bits[7:0] on pfx2.
// LDS atomics only (round-4 verified structure).
template <int MODE>
__global__ __launch_bounds__(256) void hist_pass(
    const float* __restrict__ qb, const float* __restrict__ kb,
    const float* __restrict__ rowmax_g, const float* __restrict__ rowsum_g,
    const unsigned* __restrict__ pfx_in, unsigned* __restrict__ hist_out) {
  constexpr int HB = (MODE == 2) ? 256 : 4096;
  __shared__ __align__(16) float Qs[64][68];
  __shared__ __align__(16) float Ksf[128][68];
  __shared__ unsigned hloc[HB];
  const int bh = blockIdx.x;
  const int q0 = blockIdx.y * 64;
  const int t = threadIdx.x;
  const int tx = t & 15, ty = t >> 4;
  for (int i = t; i < HB; i += 256) hloc[i] = 0u;
  const unsigned pf = pfx_in[bh];
  {
    const int c = t & 15, r0 = t >> 4;
#pragma unroll
    for (int s = 0; s < 4; s++) {
      int r = r0 + 16 * s;
      int gq = q0 + r;
      float4 v = make_float4(0.f, 0.f, 0.f, 0.f);
      if (gq < N_) v = *(const float4*)&qb[((size_t)bh * N_ + gq) * HD_ + 4 * c];
      v.x *= 0.125f; v.y *= 0.125f; v.z *= 0.125f; v.w *= 0.125f;
      *(float4*)&Qs[r][4 * c] = v;
    }
  }
  float M[4], inv[4];
#pragma unroll
  for (int i = 0; i < 4; i++) {
    int gq = q0 + tx + 16 * i;
    if (gq < N_) {
      M[i] = rowmax_g[(size_t)bh * N_ + gq];
      inv[i] = 1.f / rowsum_g[(size_t)bh * N_ + gq];
    } else { M[i] = 0.f; inv[i] = 0.f; }
  }
  for (int n0 = 0; n0 < N_; n0 += 128) {
    __syncthreads();
    {
      const int c = t & 15, r0 = t >> 4;
#pragma unroll
      for (int s = 0; s < 8; s++) {
        int r = r0 + 16 * s;
        int gn = n0 + r;
        float4 v = make_float4(0.f, 0.f, 0.f, 0.f);
        if (gn < N_) v = *(const float4*)&kb[((size_t)bh * N_ + gn) * HD_ + 4 * c];
        *(float4*)&Ksf[r][4 * c] = v;
      }
    }
    __syncthreads();
    float l[4][8];
#pragma unroll
    for (int i = 0; i < 4; i++)
#pragma unroll
      for (int j = 0; j < 8; j++) l[i][j] = 0.f;
#pragma unroll 2
    for (int d4 = 0; d4 < 16; d4++) {
      float4 a4[4], b4[8];
#pragma unroll
      for (int i = 0; i < 4; i++) a4[i] = *(const float4*)&Qs[tx + 16 * i][4 * d4];
#pragma unroll
      for (int j = 0; j < 8; j++) b4[j] = *(const float4*)&Ksf[ty + 16 * j][4 * d4];
#pragma unroll
      for (int i = 0; i < 4; i++)
#pragma unroll
        for (int j = 0; j < 8; j++) fma4(a4[i], b4[j], l[i][j]);
    }
#pragma unroll
    for (int i = 0; i < 4; i++) {
      int gq = q0 + tx + 16 * i;
#pragma unroll
      for (int j = 0; j < 8; j++) {
        if ((gq < N_) && (n0 + ty + 16 * j < N_)) {
          float e = expf(l[i][j] - M[i]);
          float v = e * inv[i];
          unsigned bits = __float_as_uint(v);
          if (MODE == 1) {
            if ((bits >> 20) == pf) atomicAdd(&hloc[(bits >> 8) & 0xFFFu], 1u);
          } else {
            if ((bits >> 8) == pf) atomicAdd(&hloc[bits & 0xFFu], 1u);
          }
        }
      }
    }
  }
  __syncthreads();
  for (int i = t; i < HB; i += 256)
    if (hloc[i]) atomicAdd(&hist_out[(size_t)bh * HB + i], hloc[i]);
}

// ------------------------------------------------------ radix-select levels
__global__ __launch_bounds__(64) void select_level(
    const unsigned* __restrict__ hist, int nbins,
    const unsigned* __restrict__ krem_in, const unsigned* __restrict__ pfx_in,
    unsigned* __restrict__ krem_out, unsigned* __restrict__ pfx_out, int shift) {
  const int bh = blockIdx.x;
  const int l = threadIdx.x;
  const int seg = nbins / 64;
  const unsigned krem = krem_in ? krem_in[bh] : KIDX_;
  const unsigned* hb = hist + (size_t)bh * nbins;
  __shared__ unsigned ps[64];
  unsigned psum = 0;
  int hi = nbins - 1 - l * seg;
  for (int i = 0; i < seg; i++) psum += hb[hi - i];
  ps[l] = psum;
  __syncthreads();
  if (l == 0) {
    unsigned cum = 0, before = 0;
    int bin = 0;
    for (int j = 0; j < 64; j++) {
      if (cum + ps[j] > krem) {
        unsigned c = cum;
        int hj = nbins - 1 - j * seg;
        for (int i = 0; i < seg; i++) {
          unsigned cnt = hb[hj - i];
          if (c + cnt > krem) { bin = hj - i; before = c; break; }
          c += cnt;
        }
        break;
      }
      cum += ps[j];
    }
    unsigned p = pfx_in ? pfx_in[bh] : 0u;
    pfx_out[bh] = (p << shift) | (unsigned)bin;
    krem_out[bh] = krem - before;
  }
}

// ------------------------------------------------- token ranking (stable)
__global__ __launch_bounds__(576) void rank_kernel(
    const float* __restrict__ ldiag, const float* __restrict__ rowmax_g,
    const float* __restrict__ rowsum_g, const unsigned* __restrict__ sigbits,
    int* __restrict__ kept) {
  const int b = blockIdx.x;
  const int i = threadIdx.x;  // token i+1
  __shared__ float sc[576];
  float s = 0.f;
  for (int h = 0; h < H_; h++) {
    int bh = b * H_ + h;
    float l = ldiag[(size_t)bh * N_ + (i + 1)];
    float M = rowmax_g[(size_t)bh * N_ + (i + 1)];
    float inv = 1.f / rowsum_g[(size_t)bh * N_ + (i + 1)];
    float e = expf(l - M);
    float v = e * inv;   // bit-identical to hist/AV computation
    float sg = __uint_as_float(sigbits[bh]);
    if (v >= sg) s = fmaxf(s, v);
  }
  sc[i] = s;
  __syncthreads();
  int r = 0;
  for (int j = 0; j < 576; j++) {
    float sj = sc[j];
    if (sj > s || (sj == s && j < i)) r++;
  }
  if (r < KK_ - 1) kept[b * KK_ + r + 1] = i + 1;
  if (i == 0) kept[b * KK_] = 0;
}

// ------------------------------------------------------ gather x_original
__global__ __launch_bounds__(256) void gather_x(
    const float* __restrict__ xo, const int* __restrict__ kept,
    float* __restrict__ out2) {
  const int bp = blockIdx.x;
  const int b = bp / KK_, p = bp % KK_;
  const int src = kept[b * KK_ + p];
  const float* s = xo + ((size_t)b * N_ + src) * C_;
  float* d = out2 + (size_t)bp * C_;
  for (int c = threadIdx.x; c < C_; c += 256) d[c] = s[c];
}

// ------------------------------------------- AV (QK recompute + PV)
__global__ __launch_bounds__(256) void av_kernel(
    const float* __restrict__ qb, const float* __restrict__ kb,
    const float* __restrict__ vb, const int* __restrict__ kept,
    const float* __restrict__ rowmax_g, const float* __restrict__ rowsum_g,
    const unsigned* __restrict__ sigbits, float* __restrict__ out1) {
  __shared__ __align__(16) float Qs[64][68];
  __shared__ __align__(16) float Ksf[64][68];   // K, then P overlay
  __shared__ __align__(16) float Vs[64][68];
  __shared__ int ridx[64];
  __shared__ float Ml[64], Il[64];
  const int bh = blockIdx.x;
  const int p0 = blockIdx.y * 64;
  const int b = bh / H_, h = bh % H_;
  const float sigma = __uint_as_float(sigbits[bh]);
  const int t = threadIdx.x;
  const int tx = t & 15, ty = t >> 4;
  if (t < 64) {
    int pp = p0 + t;
    int r = (pp < KK_) ? kept[b * KK_ + pp] : 0;
    ridx[t] = r;
    Ml[t] = rowmax_g[(size_t)bh * N_ + r];
    Il[t] = 1.f / rowsum_g[(size_t)bh * N_ + r];
  }
  __syncthreads();
  {
    const int c = t & 15, r0 = t >> 4;
#pragma unroll
    for (int s = 0; s < 4; s++) {
      int r = r0 + 16 * s;
      int gq = ridx[r];
      float4 v = *(const float4*)&qb[((size_t)bh * N_ + gq) * HD_ + 4 * c];
      v.x *= 0.125f; v.y *= 0.125f; v.z *= 0.125f; v.w *= 0.125f;
      *(float4*)&Qs[r][4 * c] = v;
    }
  }
  float M[4], inv[4];
#pragma unroll
  for (int i = 0; i < 4; i++) { int row = tx + 16 * i; M[i] = Ml[row]; inv[i] = Il[row]; }
  float acc[4][4] = {};
  for (int n0 = 0; n0 < N_; n0 += 64) {
    __syncthreads();
    {
      const int c = t & 15, r0 = t >> 4;
#pragma unroll
      for (int s = 0; s < 4; s++) {
        int r = r0 + 16 * s;
        int gn = n0 + r;
        float4 kv = make_float4(0.f, 0.f, 0.f, 0.f);
        float4 vv = make_float4(0.f, 0.f, 0.f, 0.f);
        if (gn < N_) {
          kv = *(const float4*)&kb[((size_t)bh * N_ + gn) * HD_ + 4 * c];
          vv = *(const float4*)&vb[((size_t)bh * N_ + gn) * HD_ + 4 * c];
        }
        *(float4*)&Ksf[r][4 * c] = kv;
        *(float4*)&Vs[r][4 * c] = vv;
      }
    }
    __syncthreads();
    float l[4][4];
#pragma unroll
    for (int i = 0; i < 4; i++)
#pragma unroll
      for (int j = 0; j < 4; j++) l[i][j] = 0.f;
#pragma unroll 4
    for (int d4 = 0; d4 < 16; d4++) {
      float4 a4[4], b4[4];
#pragma unroll
      for (int i = 0; i < 4; i++) a4[i] = *(const float4*)&Qs[tx + 16 * i][4 * d4];
#pragma unroll
      for (int j = 0; j < 4; j++) b4[j] = *(const float4*)&Ksf[4 * ty + j][4 * d4];
#pragma unroll
      for (int i = 0; i < 4; i++)
#pragma unroll
        for (int j = 0; j < 4; j++) fma4(a4[i], b4[j], l[i][j]);
    }
    __syncthreads();   // QK done -> overlay P on Ksf
#pragma unroll
    for (int i = 0; i < 4; i++) {
      float4 pv4;
      float* pp = (float*)&pv4;
#pragma unroll
      for (int j = 0; j < 4; j++) {
        float e = expf(l[i][j] - M[i]);
        float v = e * inv[i];
        pp[j] = (v >= sigma) ? v : 0.f;   // padded cols harmless: V=0
      }
      *(float4*)&Ksf[tx + 16 * i][4 * ty] = pv4;
    }
    __syncthreads();
#pragma unroll 4
    for (int nb = 0; nb < 16; nb++) {
      float4 pa4[4];
#pragma unroll
      for (int i = 0; i < 4; i++) pa4[i] = *(const float4*)&Ksf[tx + 16 * i][4 * nb];
#pragma unroll
      for (int e = 0; e < 4; e++) {
        float4 vv4 = *(const float4*)&Vs[4 * nb + e][4 * ty];
#pragma unroll
        for (int i = 0; i < 4; i++) {
          float pvv = ((const float*)&pa4[i])[e];
          acc[i][0] = __builtin_fmaf(pvv, vv4.x, acc[i][0]);
          acc[i][1] = __builtin_fmaf(pvv, vv4.y, acc[i][1]);
          acc[i][2] = __builtin_fmaf(pvv, vv4.z, acc[i][2]);
          acc[i][3] = __builtin_fmaf(pvv, vv4.w, acc[i][3]);
        }
      }
    }
  }
#pragma unroll
  for (int i = 0; i < 4; i++) {
    int pp = p0 + tx + 16 * i;
    if (pp >= KK_) continue;
    float4 o = make_float4(acc[i][0], acc[i][1], acc[i][2], acc[i][3]);
    *(float4*)&out1[((size_t)(b * KK_ + pp)) * C_ + h * HD_ + 4 * ty] = o;
  }
}

// ------------------------------------------------------------ proj GEMM
__global__ __launch_bounds__(256) void proj_gemm(
    const float* __restrict__ Xi, const float* __restrict__ W,
    const float* __restrict__ bias, float* __restrict__ out) {
  __shared__ __align__(16) float Xs[128][36];
  __shared__ __align__(16) float Ws2[128][36];
  const int m0 = blockIdx.x * 128;
  const int n0 = blockIdx.y * 128;
  const int t = threadIdx.x;
  const int tx = t & 15, ty = t >> 4;
  float acc[8][8] = {};
  for (int k0 = 0; k0 < 768; k0 += 32) {
    __syncthreads();
    {
      const int c = t & 7, r0 = t >> 3;
#pragma unroll
      for (int s = 0; s < 4; s++) {
        int r = r0 + 32 * s;
        float4 v = *(const float4*)&Xi[(size_t)(m0 + r) * 768 + k0 + 4 * c];
        *(float4*)&Xs[r][4 * c] = v;
        float4 w = *(const float4*)&W[(size_t)(n0 + r) * 768 + k0 + 4 * c];
        *(float4*)&Ws2[r][4 * c] = w;
      }
    }
    __syncthreads();
#pragma unroll
    for (int d4 = 0; d4 < 8; d4++) {
      float4 a4[8], b4[8];
#pragma unroll
      for (int i = 0; i < 8; i++) a4[i] = *(const float4*)&Xs[tx + 16 * i][4 * d4];
#pragma unroll
      for (int j = 0; j < 8; j++) b4[j] = *(const float4*)&Ws2[ty + 16 * j][4 * d4];
#pragma unroll
      for (int i = 0; i < 8; i++)
#pragma unroll
        for (int j = 0; j < 8; j++) fma4(a4[i], b4[j], acc[i][j]);
    }
  }
  for (int i = 0; i < 8; i++) {
    int gm = m0 + tx + 16 * i;   // M2 = 8320 = 65*128, no guard
    for (int j = 0; j < 8; j++) {
      int gn = n0 + ty + 16 * j;
      out[(size_t)gm * C_ + gn] = acc[i][j] + bias[gn];
    }
  }
}

// ---------------------------------------------------------------- launcher
extern "C" void kernel_launch(void* const* d_in, const int* in_sizes, int n_in,
                              void* d_out, int out_size, void* d_ws, size_t ws_size,
                              hipStream_t stream) {
  (void)in_sizes; (void)n_in; (void)out_size; (void)ws_size;
  const float* x    = (const float*)d_in[0];
  const float* xo   = (const float*)d_in[1];
  const float* qkvw = (const float*)d_in[2];
  const float* pw   = (const float*)d_in[3];
  const float* pb   = (const float*)d_in[4];

  char* ws = (char*)d_ws;
  size_t off = 0;
  auto alloc = [&](size_t bytes) -> char* {
    char* p = ws + off;
    off += (bytes + 255) & ~(size_t)255;
    return p;
  };
  const size_t szQ    = (size_t)BH_ * N_ * HD_ * 4;   // 28.4 MB
  const size_t szOut1 = (size_t)M2_ * C_ * 4;         // 25.6 MB
  const size_t szRow  = (size_t)BH_ * N_ * 4;         // 443 KB
  const size_t szH12  = (size_t)BH_ * 4096 * 4;       // 3.1 MB
  const size_t szH3   = (size_t)BH_ * 256 * 4;

  float* qb     = (float*)alloc(szQ);
  float* kb     = (float*)alloc(szQ);
  float* vb     = (float*)alloc(szQ);
  float* out1   = (float*)alloc(szOut1);
  float* ldiag  = (float*)alloc(szRow);
  float* rowmax = (float*)alloc(szRow);
  float* rowsum = (float*)alloc(szRow);
  unsigned* hist1 = (unsigned*)alloc(szH12);
  unsigned* hist2 = (unsigned*)alloc(szH12);
  unsigned* hist3 = (unsigned*)alloc(szH3);
  unsigned* pfx1  = (unsigned*)alloc(BH_ * 4);
  unsigned* krem1 = (unsigned*)alloc(BH_ * 4);
  unsigned* pfx2  = (unsigned*)alloc(BH_ * 4);
  unsigned* krem2 = (unsigned*)alloc(BH_ * 4);
  unsigned* sigb  = (unsigned*)alloc(BH_ * 4);
  unsigned* krem3 = (unsigned*)alloc(BH_ * 4);
  int* kept       = (int*)alloc((size_t)B_ * KK_ * 4);

  hipMemsetAsync(hist1, 0, szH12, stream);
  hipMemsetAsync(hist2, 0, szH12, stream);
  hipMemsetAsync(hist3, 0, szH3, stream);

  qkv_gemm<<<dim3(73, 18), 256, 0, stream>>>(x, qkvw, qb, kb, vb);
  stats_hist1<<<dim3(BH_, 10), 256, 0, stream>>>(qb, kb, rowmax, rowsum, ldiag, hist1);
  select_level<<<BH_, 64, 0, stream>>>(hist1, 4096, nullptr, nullptr, krem1, pfx1, 12);
  hist_pass<1><<<dim3(BH_, 10), 256, 0, stream>>>(qb, kb, rowmax, rowsum, pfx1, hist2);
  select_level<<<BH_, 64, 0, stream>>>(hist2, 4096, krem1, pfx1, krem2, pfx2, 12);
  hist_pass<2><<<dim3(BH_, 10), 256, 0, stream>>>(qb, kb, rowmax, rowsum, pfx2, hist3);
  select_level<<<BH_, 64, 0, stream>>>(hist3, 256, krem2, pfx2, krem3, sigb, 8);
  rank_kernel<<<B_, 576, 0, stream>>>(ldiag, rowmax, rowsum, sigb, kept);

  float* outp = (float*)d_out;
  gather_x<<<M2_, 256, 0, stream>>>(xo, kept, outp + (size_t)M2_ * C_);
  av_kernel<<<dim3(BH_, 9), 256, 0, stream>>>(qb, kb, vb, kept, rowmax, rowsum, sigb, out1);
  proj_gemm<<<dim3(65, 6), 256, 0, stream>>>(out1, pw, pb, outp);
}

// Round 7
// 1906.266 us; speedup vs baseline: 1.8934x; 1.1481x over previous
//
#include <hip/hip_runtime.h>
#include <cstdint>
#include <cstddef>

// Attention_41231686042092: ViT attention + softmax sparsification (per-(b,h)
// exact median threshold via 3-level radix select on f32 bit patterns) +
// diag-based token pruning + projection. All f32 (ranking needs exact-index
// fidelity; bf16 noise would flip argsort order).
//
// Round-7: best-known composition. Round-4's proven selection flow
// (separate attn_stats + hist_pass<0/1/2>, LDS-atomic histograms, 64x128
// 4x8 QK microkernel at 3 blocks/CU) + 8x8-microtile qkv/proj GEMMs.
// Round-6's stats+hist1 fusion reverted (176 VGPR + 69KB LDS -> 2 blocks/CU
// -> latency-bound, 799us vs ~340us for the separate pair).
// Every logit is a single ascending-k fmaf chain (fma4) -> bit-identical
// across all passes; M/S loaded from the same globals everywhere.

namespace {
constexpr int B_  = 16;
constexpr int N_  = 577;
constexpr int C_  = 768;
constexpr int H_  = 12;
constexpr int HD_ = 64;
constexpr int BH_ = B_ * H_;            // 192
constexpr int KK_ = N_ - 57;            // 520 kept tokens
constexpr unsigned KIDX_ = 166464u;     // int(N*N*0.5), 0-based desc rank
constexpr int M1_ = B_ * N_;            // 9232
constexpr int M2_ = B_ * KK_;           // 8320
}

__device__ __forceinline__ void fma4(const float4& a, const float4& b, float& acc) {
  acc = __builtin_fmaf(a.x, b.x, acc);
  acc = __builtin_fmaf(a.y, b.y, acc);
  acc = __builtin_fmaf(a.z, b.z, acc);
  acc = __builtin_fmaf(a.w, b.w, acc);
}

// ---------------------------------------------------------------- QKV GEMM
// Y = X @ W^T ; X:[M1,768], W:[2304,768]. 128x128 tile, 8x8 microtile, BK=32.
__global__ __launch_bounds__(256) void qkv_gemm(
    const float* __restrict__ X, const float* __restrict__ W,
    float* __restrict__ qb, float* __restrict__ kb, float* __restrict__ vb) {
  __shared__ __align__(16) float Xs[128][36];
  __shared__ __align__(16) float Ws2[128][36];
  const int m0 = blockIdx.x * 128;
  const int n0 = blockIdx.y * 128;
  const int t = threadIdx.x;
  const int tx = t & 15, ty = t >> 4;
  float acc[8][8] = {};
  for (int k0 = 0; k0 < 768; k0 += 32) {
    __syncthreads();
    {
      const int c = t & 7, r0 = t >> 3;  // 8 float4-cols, 32 rows per pass
#pragma unroll
      for (int s = 0; s < 4; s++) {
        int r = r0 + 32 * s;
        int gm = m0 + r;
        float4 v = make_float4(0.f, 0.f, 0.f, 0.f);
        if (gm < M1_) v = *(const float4*)&X[(size_t)gm * 768 + k0 + 4 * c];
        *(float4*)&Xs[r][4 * c] = v;
        float4 w = *(const float4*)&W[(size_t)(n0 + r) * 768 + k0 + 4 * c];
        *(float4*)&Ws2[r][4 * c] = w;
      }
    }
    __syncthreads();
#pragma unroll
    for (int d4 = 0; d4 < 8; d4++) {
      float4 a4[8], b4[8];
#pragma unroll
      for (int i = 0; i < 8; i++) a4[i] = *(const float4*)&Xs[tx + 16 * i][4 * d4];
#pragma unroll
      for (int j = 0; j < 8; j++) b4[j] = *(const float4*)&Ws2[ty + 16 * j][4 * d4];
#pragma unroll
      for (int i = 0; i < 8; i++)
#pragma unroll
        for (int j = 0; j < 8; j++) fma4(a4[i], b4[j], acc[i][j]);
    }
  }
  for (int i = 0; i < 8; i++) {
    int gm = m0 + tx + 16 * i;
    if (gm >= M1_) continue;
    int b = gm / N_, n = gm % N_;
    for (int j = 0; j < 8; j++) {
      int gn = n0 + ty + 16 * j;
      int which = gn / C_, rem = gn % C_;
      int h = rem >> 6, d = rem & 63;
      float* dst = (which == 0) ? qb : (which == 1) ? kb : vb;
      dst[(((size_t)(b * H_ + h)) * N_ + n) * HD_ + d] = acc[i][j];
    }
  }
}

// -------------------------------------------------- stats (QK pass #1)
// 64 q-rows/block x 5 col-tiles of 128. Online max/sum per row, logit-diag
// capture. rowmax exact (order-free); rowsum stored & reused by all passes.
__global__ __launch_bounds__(256) void attn_stats(
    const float* __restrict__ qb, const float* __restrict__ kb,
    float* __restrict__ rowmax_g, float* __restrict__ rowsum_g,
    float* __restrict__ ldiag) {
  __shared__ __align__(16) float Qs[64][68];
  __shared__ __align__(16) float Ksf[128][68];
  const int bh = blockIdx.x;
  const int q0 = blockIdx.y * 64;
  const int t = threadIdx.x;
  const int tx = t & 15, ty = t >> 4;
  {
    const int c = t & 15, r0 = t >> 4;
#pragma unroll
    for (int s = 0; s < 4; s++) {
      int r = r0 + 16 * s;
      int gq = q0 + r;
      float4 v = make_float4(0.f, 0.f, 0.f, 0.f);
      if (gq < N_) v = *(const float4*)&qb[((size_t)bh * N_ + gq) * HD_ + 4 * c];
      v.x *= 0.125f; v.y *= 0.125f; v.z *= 0.125f; v.w *= 0.125f;
      *(float4*)&Qs[r][4 * c] = v;
    }
  }
  float m[4], ss[4];
#pragma unroll
  for (int i = 0; i < 4; i++) { m[i] = -INFINITY; ss[i] = 0.f; }
  for (int n0 = 0; n0 < N_; n0 += 128) {
    __syncthreads();
    {
      const int c = t & 15, r0 = t >> 4;
#pragma unroll
      for (int s = 0; s < 8; s++) {
        int r = r0 + 16 * s;
        int gn = n0 + r;
        float4 v = make_float4(0.f, 0.f, 0.f, 0.f);
        if (gn < N_) v = *(const float4*)&kb[((size_t)bh * N_ + gn) * HD_ + 4 * c];
        *(float4*)&Ksf[r][4 * c] = v;
      }
    }
    __syncthreads();
    float l[4][8];
#pragma unroll
    for (int i = 0; i < 4; i++)
#pragma unroll
      for (int j = 0; j < 8; j++) l[i][j] = 0.f;
#pragma unroll 2
    for (int d4 = 0; d4 < 16; d4++) {
      float4 a4[4], b4[8];
#pragma unroll
      for (int i = 0; i < 4; i++) a4[i] = *(const float4*)&Qs[tx + 16 * i][4 * d4];
#pragma unroll
      for (int j = 0; j < 8; j++) b4[j] = *(const float4*)&Ksf[ty + 16 * j][4 * d4];
#pragma unroll
      for (int i = 0; i < 4; i++)
#pragma unroll
        for (int j = 0; j < 8; j++) fma4(a4[i], b4[j], l[i][j]);
    }
#pragma unroll
    for (int i = 0; i < 4; i++) {
      int gq = q0 + tx + 16 * i;
      float tmax = -INFINITY;
#pragma unroll
      for (int j = 0; j < 8; j++)
        if (n0 + ty + 16 * j < N_) tmax = fmaxf(tmax, l[i][j]);
      float mn = fmaxf(m[i], tmax);
      ss[i] *= expf(m[i] - mn);
#pragma unroll
      for (int j = 0; j < 8; j++) {
        int col = n0 + ty + 16 * j;
        if (col < N_) {
          ss[i] += expf(l[i][j] - mn);
          if (col == gq) ldiag[(size_t)bh * N_ + gq] = l[i][j];
        }
      }
      m[i] = mn;
    }
  }
  __syncthreads();
  float* Mred = &Ksf[0][0];   // overlay (Ksf dead): 64x16 each
  float* Sred = &Ksf[0][0] + 1024;
#pragma unroll
  for (int i = 0; i < 4; i++) {
    int row = tx + 16 * i;
    Mred[row * 16 + ty] = m[i];
    Sred[row * 16 + ty] = ss[i];
  }
  __syncthreads();
  if (t < 64) {
    int gq = q0 + t;
    if (gq < N_) {
      float M = -INFINITY;
      for (int k = 0; k < 16; k++) M = fmaxf(M, Mred[t * 16 + k]);
      float S = 0.f;
      for (int k = 0; k < 16; k++) S += expf(Mred[t * 16 + k] - M) * Sred[t * 16 + k];
      rowmax_g[(size_t)bh * N_ + gq] = M;
      rowsum_g[(size_t)bh * N_ + gq] = S;
    }
  }
}

// ----------------------------------------- histogram passes (QK #2,#3,#4)
// MODE 0: top-12-bit hist (ballot-coalesced LDS atomics).
// MODE 1: bits[19:8] on pfx1.  MODE 2: bits[7:0] on pfx2.
template <int MODE>
__global__ __launch_bounds__(256) void hist_pass(
    const float* __restrict__ qb, const float* __restrict__ kb,
    const float* __restrict__ rowmax_g, const float* __restrict__ rowsum_g,
    const unsigned* __restrict__ pfx_in, unsigned* __restrict__ hist_out) {
  constexpr int HB = (MODE == 2) ? 256 : 4096;
  __shared__ __align__(16) float Qs[64][68];
  __shared__ __align__(16) float Ksf[128][68];
  __shared__ unsigned hloc[HB];
  const int bh = blockIdx.x;
  const int q0 = blockIdx.y * 64;
  const int t = threadIdx.x;
  const int tx = t & 15, ty = t >> 4;
  for (int i = t; i < HB; i += 256) hloc[i] = 0u;
  const unsigned pf = (MODE == 0) ? 0u : pfx_in[bh];
  {
    const int c = t & 15, r0 = t >> 4;
#pragma unroll
    for (int s = 0; s < 4; s++) {
      int r = r0 + 16 * s;
      int gq = q0 + r;
      float4 v = make_float4(0.f, 0.f, 0.f, 0.f);
      if (gq < N_) v = *(const float4*)&qb[((size_t)bh * N_ + gq) * HD_ + 4 * c];
      v.x *= 0.125f; v.y *= 0.125f; v.z *= 0.125f; v.w *= 0.125f;
      *(float4*)&Qs[r][4 * c] = v;
    }
  }
  float M[4], inv[4];
#pragma unroll
  for (int i = 0; i < 4; i++) {
    int gq = q0 + tx + 16 * i;
    if (gq < N_) {
      M[i] = rowmax_g[(size_t)bh * N_ + gq];
      inv[i] = 1.f / rowsum_g[(size_t)bh * N_ + gq];
    } else { M[i] = 0.f; inv[i] = 0.f; }
  }
  for (int n0 = 0; n0 < N_; n0 += 128) {
    __syncthreads();
    {
      const int c = t & 15, r0 = t >> 4;
#pragma unroll
      for (int s = 0; s < 8; s++) {
        int r = r0 + 16 * s;
        int gn = n0 + r;
        float4 v = make_float4(0.f, 0.f, 0.f, 0.f);
        if (gn < N_) v = *(const float4*)&kb[((size_t)bh * N_ + gn) * HD_ + 4 * c];
        *(float4*)&Ksf[r][4 * c] = v;
      }
    }
    __syncthreads();
    float l[4][8];
#pragma unroll
    for (int i = 0; i < 4; i++)
#pragma unroll
      for (int j = 0; j < 8; j++) l[i][j] = 0.f;
#pragma unroll 2
    for (int d4 = 0; d4 < 16; d4++) {
      float4 a4[4], b4[8];
#pragma unroll
      for (int i = 0; i < 4; i++) a4[i] = *(const float4*)&Qs[tx + 16 * i][4 * d4];
#pragma unroll
      for (int j = 0; j < 8; j++) b4[j] = *(const float4*)&Ksf[ty + 16 * j][4 * d4];
#pragma unroll
      for (int i = 0; i < 4; i++)
#pragma unroll
        for (int j = 0; j < 8; j++) fma4(a4[i], b4[j], l[i][j]);
    }
#pragma unroll
    for (int i = 0; i < 4; i++) {
      int gq = q0 + tx + 16 * i;
#pragma unroll
      for (int j = 0; j < 8; j++) {
        bool valid = (gq < N_) && (n0 + ty + 16 * j < N_);
        if (MODE == 0) {
          unsigned bin = 0xFFFFu;
          if (valid) {
            float e = expf(l[i][j] - M[i]);
            float v = e * inv[i];
            bin = __float_as_uint(v) >> 20;
          }
          unsigned lead = (unsigned)__builtin_amdgcn_readfirstlane((int)bin);
          unsigned long long mm = __ballot(bin == lead);
          if (bin == lead) {
            if (lead != 0xFFFFu && (t & 63) == (__ffsll((unsigned long long)mm) - 1))
              atomicAdd(&hloc[lead], (unsigned)__popcll(mm));
          } else if (bin != 0xFFFFu) {
            atomicAdd(&hloc[bin], 1u);
          }
        } else if (valid) {
          float e = expf(l[i][j] - M[i]);
          float v = e * inv[i];
          unsigned bits = __float_as_uint(v);
          if (MODE == 1) {
            if ((bits >> 20) == pf) atomicAdd(&hloc[(bits >> 8) & 0xFFFu], 1u);
          } else {
            if ((bits >> 8) == pf) atomicAdd(&hloc[bits & 0xFFu], 1u);
          }
        }
      }
    }
  }
  __syncthreads();
  for (int i = t; i < HB; i += 256)
    if (hloc[i]) atomicAdd(&hist_out[(size_t)bh * HB + i], hloc[i]);
}

// ------------------------------------------------------ radix-select levels
__global__ __launch_bounds__(64) void select_level(
    const unsigned* __restrict__ hist, int nbins,
    const unsigned* __restrict__ krem_in, const unsigned* __restrict__ pfx_in,
    unsigned* __restrict__ krem_out, unsigned* __restrict__ pfx_out, int shift) {
  const int bh = blockIdx.x;
  const int l = threadIdx.x;
  const int seg = nbins / 64;
  const unsigned krem = krem_in ? krem_in[bh] : KIDX_;
  const unsigned* hb = hist + (size_t)bh * nbins;
  __shared__ unsigned ps[64];
  unsigned psum = 0;
  int hi = nbins - 1 - l * seg;
  for (int i = 0; i < seg; i++) psum += hb[hi - i];
  ps[l] = psum;
  __syncthreads();
  if (l == 0) {
    unsigned cum = 0, before = 0;
    int bin = 0;
    for (int j = 0; j < 64; j++) {
      if (cum + ps[j] > krem) {
        unsigned c = cum;
        int hj = nbins - 1 - j * seg;
        for (int i = 0; i < seg; i++) {
          unsigned cnt = hb[hj - i];
          if (c + cnt > krem) { bin = hj - i; before = c; break; }
          c += cnt;
        }
        break;
      }
      cum += ps[j];
    }
    unsigned p = pfx_in ? pfx_in[bh] : 0u;
    pfx_out[bh] = (p << shift) | (unsigned)bin;
    krem_out[bh] = krem - before;
  }
}

// ------------------------------------------------- token ranking (stable)
__global__ __launch_bounds__(576) void rank_kernel(
    const float* __restrict__ ldiag, const float* __restrict__ rowmax_g,
    const float* __restrict__ rowsum_g, const unsigned* __restrict__ sigbits,
    int* __restrict__ kept) {
  const int b = blockIdx.x;
  const int i = threadIdx.x;  // token i+1
  __shared__ float sc[576];
  float s = 0.f;
  for (int h = 0; h < H_; h++) {
    int bh = b * H_ + h;
    float l = ldiag[(size_t)bh * N_ + (i + 1)];
    float M = rowmax_g[(size_t)bh * N_ + (i + 1)];
    float inv = 1.f / rowsum_g[(size_t)bh * N_ + (i + 1)];
    float e = expf(l - M);
    float v = e * inv;   // bit-identical to hist/AV computation
    float sg = __uint_as_float(sigbits[bh]);
    if (v >= sg) s = fmaxf(s, v);
  }
  sc[i] = s;
  __syncthreads();
  int r = 0;
  for (int j = 0; j < 576; j++) {
    float sj = sc[j];
    if (sj > s || (sj == s && j < i)) r++;
  }
  if (r < KK_ - 1) kept[b * KK_ + r + 1] = i + 1;
  if (i == 0) kept[b * KK_] = 0;
}

// ------------------------------------------------------ gather x_original
__global__ __launch_bounds__(256) void gather_x(
    const float* __restrict__ xo, const int* __restrict__ kept,
    float* __restrict__ out2) {
  const int bp = blockIdx.x;
  const int b = bp / KK_, p = bp % KK_;
  const int src = kept[b * KK_ + p];
  const float* s = xo + ((size_t)b * N_ + src) * C_;
  float* d = out2 + (size_t)bp * C_;
  for (int c = threadIdx.x; c < C_; c += 256) d[c] = s[c];
}

// ------------------------------------------- AV (QK recompute + PV)
__global__ __launch_bounds__(256) void av_kernel(
    const float* __restrict__ qb, const float* __restrict__ kb,
    const float* __restrict__ vb, const int* __restrict__ kept,
    const float* __restrict__ rowmax_g, const float* __restrict__ rowsum_g,
    const unsigned* __restrict__ sigbits, float* __restrict__ out1) {
  __shared__ __align__(16) float Qs[64][68];
  __shared__ __align__(16) float Ksf[64][68];   // K, then P overlay
  __shared__ __align__(16) float Vs[64][68];
  __shared__ int ridx[64];
  __shared__ float Ml[64], Il[64];
  const int bh = blockIdx.x;
  const int p0 = blockIdx.y * 64;
  const int b = bh / H_, h = bh % H_;
  const float sigma = __uint_as_float(sigbits[bh]);
  const int t = threadIdx.x;
  const int tx = t & 15, ty = t >> 4;
  if (t < 64) {
    int pp = p0 + t;
    int r = (pp < KK_) ? kept[b * KK_ + pp] : 0;
    ridx[t] = r;
    Ml[t] = rowmax_g[(size_t)bh * N_ + r];
    Il[t] = 1.f / rowsum_g[(size_t)bh * N_ + r];
  }
  __syncthreads();
  {
    const int c = t & 15, r0 = t >> 4;
#pragma unroll
    for (int s = 0; s < 4; s++) {
      int r = r0 + 16 * s;
      int gq = ridx[r];
      float4 v = *(const float4*)&qb[((size_t)bh * N_ + gq) * HD_ + 4 * c];
      v.x *= 0.125f; v.y *= 0.125f; v.z *= 0.125f; v.w *= 0.125f;
      *(float4*)&Qs[r][4 * c] = v;
    }
  }
  float M[4], inv[4];
#pragma unroll
  for (int i = 0; i < 4; i++) { int row = tx + 16 * i; M[i] = Ml[row]; inv[i] = Il[row]; }
  float acc[4][4] = {};
  for (int n0 = 0; n0 < N_; n0 += 64) {
    __syncthreads();
    {
      const int c = t & 15, r0 = t >> 4;
#pragma unroll
      for (int s = 0; s < 4; s++) {
        int r = r0 + 16 * s;
        int gn = n0 + r;
        float4 kv = make_float4(0.f, 0.f, 0.f, 0.f);
        float4 vv = make_float4(0.f, 0.f, 0.f, 0.f);
        if (gn < N_) {
          kv = *(const float4*)&kb[((size_t)bh * N_ + gn) * HD_ + 4 * c];
          vv = *(const float4*)&vb[((size_t)bh * N_ + gn) * HD_ + 4 * c];
        }
        *(float4*)&Ksf[r][4 * c] = kv;
        *(float4*)&Vs[r][4 * c] = vv;
      }
    }
    __syncthreads();
    float l[4][4];
#pragma unroll
    for (int i = 0; i < 4; i++)
#pragma unroll
      for (int j = 0; j < 4; j++) l[i][j] = 0.f;
#pragma unroll 4
    for (int d4 = 0; d4 < 16; d4++) {
      float4 a4[4], b4[4];
#pragma unroll
      for (int i = 0; i < 4; i++) a4[i] = *(const float4*)&Qs[tx + 16 * i][4 * d4];
#pragma unroll
      for (int j = 0; j < 4; j++) b4[j] = *(const float4*)&Ksf[4 * ty + j][4 * d4];
#pragma unroll
      for (int i = 0; i < 4; i++)
#pragma unroll
        for (int j = 0; j < 4; j++) fma4(a4[i], b4[j], l[i][j]);
    }
    __syncthreads();   // QK done -> overlay P on Ksf
#pragma unroll
    for (int i = 0; i < 4; i++) {
      float4 pv4;
      float* pp = (float*)&pv4;
#pragma unroll
      for (int j = 0; j < 4; j++) {
        float e = expf(l[i][j] - M[i]);
        float v = e * inv[i];
        pp[j] = (v >= sigma) ? v : 0.f;   // padded cols harmless: V=0
      }
      *(float4*)&Ksf[tx + 16 * i][4 * ty] = pv4;
    }
    __syncthreads();
#pragma unroll 4
    for (int nb = 0; nb < 16; nb++) {
      float4 pa4[4];
#pragma unroll
      for (int i = 0; i < 4; i++) pa4[i] = *(const float4*)&Ksf[tx + 16 * i][4 * nb];
#pragma unroll
      for (int e = 0; e < 4; e++) {
        float4 vv4 = *(const float4*)&Vs[4 * nb + e][4 * ty];
#pragma unroll
        for (int i = 0; i < 4; i++) {
          float pvv = ((const float*)&pa4[i])[e];
          acc[i][0] = __builtin_fmaf(pvv, vv4.x, acc[i][0]);
          acc[i][1] = __builtin_fmaf(pvv, vv4.y, acc[i][1]);
          acc[i][2] = __builtin_fmaf(pvv, vv4.z, acc[i][2]);
          acc[i][3] = __builtin_fmaf(pvv, vv4.w, acc[i][3]);
        }
      }
    }
  }
#pragma unroll
  for (int i = 0; i < 4; i++) {
    int pp = p0 + tx + 16 * i;
    if (pp >= KK_) continue;
    float4 o = make_float4(acc[i][0], acc[i][1], acc[i][2], acc[i][3]);
    *(float4*)&out1[((size_t)(b * KK_ + pp)) * C_ + h * HD_ + 4 * ty] = o;
  }
}

// ------------------------------------------------------------ proj GEMM
__global__ __launch_bounds__(256) void proj_gemm(
    const float* __restrict__ Xi, const float* __restrict__ W,
    const float* __restrict__ bias, float* __restrict__ out) {
  __shared__ __align__(16) float Xs[128][36];
  __shared__ __align__(16) float Ws2[128][36];
  const int m0 = blockIdx.x * 128;
  const int n0 = blockIdx.y * 128;
  const int t = threadIdx.x;
  const int tx = t & 15, ty = t >> 4;
  float acc[8][8] = {};
  for (int k0 = 0; k0 < 768; k0 += 32) {
    __syncthreads();
    {
      const int c = t & 7, r0 = t >> 3;
#pragma unroll
      for (int s = 0; s < 4; s++) {
        int r = r0 + 32 * s;
        float4 v = *(const float4*)&Xi[(size_t)(m0 + r) * 768 + k0 + 4 * c];
        *(float4*)&Xs[r][4 * c] = v;
        float4 w = *(const float4*)&W[(size_t)(n0 + r) * 768 + k0 + 4 * c];
        *(float4*)&Ws2[r][4 * c] = w;
      }
    }
    __syncthreads();
#pragma unroll
    for (int d4 = 0; d4 < 8; d4++) {
      float4 a4[8], b4[8];
#pragma unroll
      for (int i = 0; i < 8; i++) a4[i] = *(const float4*)&Xs[tx + 16 * i][4 * d4];
#pragma unroll
      for (int j = 0; j < 8; j++) b4[j] = *(const float4*)&Ws2[ty + 16 * j][4 * d4];
#pragma unroll
      for (int i = 0; i < 8; i++)
#pragma unroll
        for (int j = 0; j < 8; j++) fma4(a4[i], b4[j], acc[i][j]);
    }
  }
  for (int i = 0; i < 8; i++) {
    int gm = m0 + tx + 16 * i;   // M2 = 8320 = 65*128, no guard
    for (int j = 0; j < 8; j++) {
      int gn = n0 + ty + 16 * j;
      out[(size_t)gm * C_ + gn] = acc[i][j] + bias[gn];
    }
  }
}

// ---------------------------------------------------------------- launcher
extern "C" void kernel_launch(void* const* d_in, const int* in_sizes, int n_in,
                              void* d_out, int out_size, void* d_ws, size_t ws_size,
                              hipStream_t stream) {
  (void)in_sizes; (void)n_in; (void)out_size; (void)ws_size;
  const float* x    = (const float*)d_in[0];
  const float* xo   = (const float*)d_in[1];
  const float* qkvw = (const float*)d_in[2];
  const float* pw   = (const float*)d_in[3];
  const float* pb   = (const float*)d_in[4];

  char* ws = (char*)d_ws;
  size_t off = 0;
  auto alloc = [&](size_t bytes) -> char* {
    char* p = ws + off;
    off += (bytes + 255) & ~(size_t)255;
    return p;
  };
  const size_t szQ    = (size_t)BH_ * N_ * HD_ * 4;   // 28.4 MB
  const size_t szOut1 = (size_t)M2_ * C_ * 4;         // 25.6 MB
  const size_t szRow  = (size_t)BH_ * N_ * 4;         // 443 KB
  const size_t szH12  = (size_t)BH_ * 4096 * 4;       // 3.1 MB
  const size_t szH3   = (size_t)BH_ * 256 * 4;

  float* qb     = (float*)alloc(szQ);
  float* kb     = (float*)alloc(szQ);
  float* vb     = (float*)alloc(szQ);
  float* out1   = (float*)alloc(szOut1);
  float* ldiag  = (float*)alloc(szRow);
  float* rowmax = (float*)alloc(szRow);
  float* rowsum = (float*)alloc(szRow);
  unsigned* hist1 = (unsigned*)alloc(szH12);
  unsigned* hist2 = (unsigned*)alloc(szH12);
  unsigned* hist3 = (unsigned*)alloc(szH3);
  unsigned* pfx1  = (unsigned*)alloc(BH_ * 4);
  unsigned* krem1 = (unsigned*)alloc(BH_ * 4);
  unsigned* pfx2  = (unsigned*)alloc(BH_ * 4);
  unsigned* krem2 = (unsigned*)alloc(BH_ * 4);
  unsigned* sigb  = (unsigned*)alloc(BH_ * 4);
  unsigned* krem3 = (unsigned*)alloc(BH_ * 4);
  int* kept       = (int*)alloc((size_t)B_ * KK_ * 4);

  hipMemsetAsync(hist1, 0, szH12, stream);
  hipMemsetAsync(hist2, 0, szH12, stream);
  hipMemsetAsync(hist3, 0, szH3, stream);

  qkv_gemm<<<dim3(73, 18), 256, 0, stream>>>(x, qkvw, qb, kb, vb);
  attn_stats<<<dim3(BH_, 10), 256, 0, stream>>>(qb, kb, rowmax, rowsum, ldiag);
  hist_pass<0><<<dim3(BH_, 10), 256, 0, stream>>>(qb, kb, rowmax, rowsum, nullptr, hist1);
  select_level<<<BH_, 64, 0, stream>>>(hist1, 4096, nullptr, nullptr, krem1, pfx1, 12);
  hist_pass<1><<<dim3(BH_, 10), 256, 0, stream>>>(qb, kb, rowmax, rowsum, pfx1, hist2);
  select_level<<<BH_, 64, 0, stream>>>(hist2, 4096, krem1, pfx1, krem2, pfx2, 12);
  hist_pass<2><<<dim3(BH_, 10), 256, 0, stream>>>(qb, kb, rowmax, rowsum, pfx2, hist3);
  select_level<<<BH_, 64, 0, stream>>>(hist3, 256, krem2, pfx2, krem3, sigb, 8);
  rank_kernel<<<B_, 576, 0, stream>>>(ldiag, rowmax, rowsum, sigb, kept);

  float* outp = (float*)d_out;
  gather_x<<<M2_, 256, 0, stream>>>(xo, kept, outp + (size_t)M2_ * C_);
  av_kernel<<<dim3(BH_, 9), 256, 0, stream>>>(qb, kb, vb, kept, rowmax, rowsum, sigb, out1);
  proj_gemm<<<dim3(65, 6), 256, 0, stream>>>(out1, pw, pb, outp);
}

// Round 8
// 1673.128 us; speedup vs baseline: 2.1573x; 1.1393x over previous
//
#include <hip/hip_runtime.h>
#include <cstdint>
#include <cstddef>

// Attention_41231686042092: ViT attention + softmax sparsification (per-(b,h)
// exact median threshold via 3-level radix select on f32 bit patterns) +
// diag-based token pruning + projection.
//
// Round-8: (1) qkv reverted to round-4's 64x128/4x8 f32 kernel (measured 526us;
// round-7's 128^2/8x8 was 627us — occupancy regression). (2) proj rewritten as
// bf16 MFMA (16x16x32) with 2-way hi/lo split, 3 terms — error ~2e-5 abs vs
// 0.108 threshold; proj is downstream of all ranking so zero index risk.
// Pathfinder for MFMA-izing the QK passes next round.
// Selection passes unchanged: single ascending-k fmaf chains, shared M/S.

namespace {
constexpr int B_  = 16;
constexpr int N_  = 577;
constexpr int C_  = 768;
constexpr int H_  = 12;
constexpr int HD_ = 64;
constexpr int BH_ = B_ * H_;            // 192
constexpr int KK_ = N_ - 57;            // 520 kept tokens
constexpr unsigned KIDX_ = 166464u;     // int(N*N*0.5), 0-based desc rank
constexpr int M1_ = B_ * N_;            // 9232
constexpr int M2_ = B_ * KK_;           // 8320
}

typedef __attribute__((ext_vector_type(8))) short bfx8;
typedef __attribute__((ext_vector_type(4))) float fx4;

__device__ __forceinline__ void fma4(const float4& a, const float4& b, float& acc) {
  acc = __builtin_fmaf(a.x, b.x, acc);
  acc = __builtin_fmaf(a.y, b.y, acc);
  acc = __builtin_fmaf(a.z, b.z, acc);
  acc = __builtin_fmaf(a.w, b.w, acc);
}

__device__ __forceinline__ unsigned short f2bf(float x) {
  unsigned u = __float_as_uint(x);
  unsigned r = u + 0x7FFFu + ((u >> 16) & 1u);
  return (unsigned short)(r >> 16);
}
__device__ __forceinline__ float bf2f(unsigned short h) {
  return __uint_as_float(((unsigned)h) << 16);
}

// ---------------------------------------------------------------- QKV GEMM
// Round-4 version: 64x128 tile, 4x8 microtile, k-chunk 64 (measured 526us).
__global__ __launch_bounds__(256) void qkv_gemm(
    const float* __restrict__ X, const float* __restrict__ W,
    float* __restrict__ qb, float* __restrict__ kb, float* __restrict__ vb) {
  __shared__ __align__(16) float Xs[64][68];
  __shared__ __align__(16) float Ws2[128][68];
  const int m0 = blockIdx.x * 64;
  const int n0 = blockIdx.y * 128;
  const int t = threadIdx.x;
  const int tx = t & 15, ty = t >> 4;
  float acc[4][8] = {};
  for (int k0 = 0; k0 < 768; k0 += 64) {
    __syncthreads();
    {
      const int c = t & 15, r0 = t >> 4;
#pragma unroll
      for (int s = 0; s < 4; s++) {
        int r = r0 + 16 * s;
        int gm = m0 + r;
        float4 v = make_float4(0.f, 0.f, 0.f, 0.f);
        if (gm < M1_) v = *(const float4*)&X[(size_t)gm * 768 + k0 + 4 * c];
        *(float4*)&Xs[r][4 * c] = v;
      }
#pragma unroll
      for (int s = 0; s < 8; s++) {
        int r = r0 + 16 * s;
        float4 v = *(const float4*)&W[(size_t)(n0 + r) * 768 + k0 + 4 * c];
        *(float4*)&Ws2[r][4 * c] = v;
      }
    }
    __syncthreads();
#pragma unroll 2
    for (int d4 = 0; d4 < 16; d4++) {
      float4 a4[4], b4[8];
#pragma unroll
      for (int i = 0; i < 4; i++) a4[i] = *(const float4*)&Xs[tx + 16 * i][4 * d4];
#pragma unroll
      for (int j = 0; j < 8; j++) b4[j] = *(const float4*)&Ws2[ty + 16 * j][4 * d4];
#pragma unroll
      for (int i = 0; i < 4; i++)
#pragma unroll
        for (int j = 0; j < 8; j++) fma4(a4[i], b4[j], acc[i][j]);
    }
  }
  for (int i = 0; i < 4; i++) {
    int gm = m0 + tx + 16 * i;
    if (gm >= M1_) continue;
    int b = gm / N_, n = gm % N_;
    for (int j = 0; j < 8; j++) {
      int gn = n0 + ty + 16 * j;
      int which = gn / C_, rem = gn % C_;
      int h = rem >> 6, d = rem & 63;
      float* dst = (which == 0) ? qb : (which == 1) ? kb : vb;
      dst[(((size_t)(b * H_ + h)) * N_ + n) * HD_ + d] = acc[i][j];
    }
  }
}

// -------------------------------------------------- stats (QK pass #1)
__global__ __launch_bounds__(256) void attn_stats(
    const float* __restrict__ qb, const float* __restrict__ kb,
    float* __restrict__ rowmax_g, float* __restrict__ rowsum_g,
    float* __restrict__ ldiag) {
  __shared__ __align__(16) float Qs[64][68];
  __shared__ __align__(16) float Ksf[128][68];
  const int bh = blockIdx.x;
  const int q0 = blockIdx.y * 64;
  const int t = threadIdx.x;
  const int tx = t & 15, ty = t >> 4;
  {
    const int c = t & 15, r0 = t >> 4;
#pragma unroll
    for (int s = 0; s < 4; s++) {
      int r = r0 + 16 * s;
      int gq = q0 + r;
      float4 v = make_float4(0.f, 0.f, 0.f, 0.f);
      if (gq < N_) v = *(const float4*)&qb[((size_t)bh * N_ + gq) * HD_ + 4 * c];
      v.x *= 0.125f; v.y *= 0.125f; v.z *= 0.125f; v.w *= 0.125f;
      *(float4*)&Qs[r][4 * c] = v;
    }
  }
  float m[4], ss[4];
#pragma unroll
  for (int i = 0; i < 4; i++) { m[i] = -INFINITY; ss[i] = 0.f; }
  for (int n0 = 0; n0 < N_; n0 += 128) {
    __syncthreads();
    {
      const int c = t & 15, r0 = t >> 4;
#pragma unroll
      for (int s = 0; s < 8; s++) {
        int r = r0 + 16 * s;
        int gn = n0 + r;
        float4 v = make_float4(0.f, 0.f, 0.f, 0.f);
        if (gn < N_) v = *(const float4*)&kb[((size_t)bh * N_ + gn) * HD_ + 4 * c];
        *(float4*)&Ksf[r][4 * c] = v;
      }
    }
    __syncthreads();
    float l[4][8];
#pragma unroll
    for (int i = 0; i < 4; i++)
#pragma unroll
      for (int j = 0; j < 8; j++) l[i][j] = 0.f;
#pragma unroll 2
    for (int d4 = 0; d4 < 16; d4++) {
      float4 a4[4], b4[8];
#pragma unroll
      for (int i = 0; i < 4; i++) a4[i] = *(const float4*)&Qs[tx + 16 * i][4 * d4];
#pragma unroll
      for (int j = 0; j < 8; j++) b4[j] = *(const float4*)&Ksf[ty + 16 * j][4 * d4];
#pragma unroll
      for (int i = 0; i < 4; i++)
#pragma unroll
        for (int j = 0; j < 8; j++) fma4(a4[i], b4[j], l[i][j]);
    }
#pragma unroll
    for (int i = 0; i < 4; i++) {
      int gq = q0 + tx + 16 * i;
      float tmax = -INFINITY;
#pragma unroll
      for (int j = 0; j < 8; j++)
        if (n0 + ty + 16 * j < N_) tmax = fmaxf(tmax, l[i][j]);
      float mn = fmaxf(m[i], tmax);
      ss[i] *= expf(m[i] - mn);
#pragma unroll
      for (int j = 0; j < 8; j++) {
        int col = n0 + ty + 16 * j;
        if (col < N_) {
          ss[i] += expf(l[i][j] - mn);
          if (col == gq) ldiag[(size_t)bh * N_ + gq] = l[i][j];
        }
      }
      m[i] = mn;
    }
  }
  __syncthreads();
  float* Mred = &Ksf[0][0];   // overlay (Ksf dead): 64x16 each
  float* Sred = &Ksf[0][0] + 1024;
#pragma unroll
  for (int i = 0; i < 4; i++) {
    int row = tx + 16 * i;
    Mred[row * 16 + ty] = m[i];
    Sred[row * 16 + ty] = ss[i];
  }
  __syncthreads();
  if (t < 64) {
    int gq = q0 + t;
    if (gq < N_) {
      float M = -INFINITY;
      for (int k = 0; k < 16; k++) M = fmaxf(M, Mred[t * 16 + k]);
      float S = 0.f;
      for (int k = 0; k < 16; k++) S += expf(Mred[t * 16 + k] - M) * Sred[t * 16 + k];
      rowmax_g[(size_t)bh * N_ + gq] = M;
      rowsum_g[(size_t)bh * N_ + gq] = S;
    }
  }
}

// ----------------------------------------- histogram passes (QK #2,#3,#4)
template <int MODE>
__global__ __launch_bounds__(256) void hist_pass(
    const float* __restrict__ qb, const float* __restrict__ kb,
    const float* __restrict__ rowmax_g, const float* __restrict__ rowsum_g,
    const unsigned* __restrict__ pfx_in, unsigned* __restrict__ hist_out) {
  constexpr int HB = (MODE == 2) ? 256 : 4096;
  __shared__ __align__(16) float Qs[64][68];
  __shared__ __align__(16) float Ksf[128][68];
  __shared__ unsigned hloc[HB];
  const int bh = blockIdx.x;
  const int q0 = blockIdx.y * 64;
  const int t = threadIdx.x;
  const int tx = t & 15, ty = t >> 4;
  for (int i = t; i < HB; i += 256) hloc[i] = 0u;
  const unsigned pf = (MODE == 0) ? 0u : pfx_in[bh];
  {
    const int c = t & 15, r0 = t >> 4;
#pragma unroll
    for (int s = 0; s < 4; s++) {
      int r = r0 + 16 * s;
      int gq = q0 + r;
      float4 v = make_float4(0.f, 0.f, 0.f, 0.f);
      if (gq < N_) v = *(const float4*)&qb[((size_t)bh * N_ + gq) * HD_ + 4 * c];
      v.x *= 0.125f; v.y *= 0.125f; v.z *= 0.125f; v.w *= 0.125f;
      *(float4*)&Qs[r][4 * c] = v;
    }
  }
  float M[4], inv[4];
#pragma unroll
  for (int i = 0; i < 4; i++) {
    int gq = q0 + tx + 16 * i;
    if (gq < N_) {
      M[i] = rowmax_g[(size_t)bh * N_ + gq];
      inv[i] = 1.f / rowsum_g[(size_t)bh * N_ + gq];
    } else { M[i] = 0.f; inv[i] = 0.f; }
  }
  for (int n0 = 0; n0 < N_; n0 += 128) {
    __syncthreads();
    {
      const int c = t & 15, r0 = t >> 4;
#pragma unroll
      for (int s = 0; s < 8; s++) {
        int r = r0 + 16 * s;
        int gn = n0 + r;
        float4 v = make_float4(0.f, 0.f, 0.f, 0.f);
        if (gn < N_) v = *(const float4*)&kb[((size_t)bh * N_ + gn) * HD_ + 4 * c];
        *(float4*)&Ksf[r][4 * c] = v;
      }
    }
    __syncthreads();
    float l[4][8];
#pragma unroll
    for (int i = 0; i < 4; i++)
#pragma unroll
      for (int j = 0; j < 8; j++) l[i][j] = 0.f;
#pragma unroll 2
    for (int d4 = 0; d4 < 16; d4++) {
      float4 a4[4], b4[8];
#pragma unroll
      for (int i = 0; i < 4; i++) a4[i] = *(const float4*)&Qs[tx + 16 * i][4 * d4];
#pragma unroll
      for (int j = 0; j < 8; j++) b4[j] = *(const float4*)&Ksf[ty + 16 * j][4 * d4];
#pragma unroll
      for (int i = 0; i < 4; i++)
#pragma unroll
        for (int j = 0; j < 8; j++) fma4(a4[i], b4[j], l[i][j]);
    }
#pragma unroll
    for (int i = 0; i < 4; i++) {
      int gq = q0 + tx + 16 * i;
#pragma unroll
      for (int j = 0; j < 8; j++) {
        bool valid = (gq < N_) && (n0 + ty + 16 * j < N_);
        if (MODE == 0) {
          unsigned bin = 0xFFFFu;
          if (valid) {
            float e = expf(l[i][j] - M[i]);
            float v = e * inv[i];
            bin = __float_as_uint(v) >> 20;
          }
          unsigned lead = (unsigned)__builtin_amdgcn_readfirstlane((int)bin);
          unsigned long long mm = __ballot(bin == lead);
          if (bin == lead) {
            if (lead != 0xFFFFu && (t & 63) == (__ffsll((unsigned long long)mm) - 1))
              atomicAdd(&hloc[lead], (unsigned)__popcll(mm));
          } else if (bin != 0xFFFFu) {
            atomicAdd(&hloc[bin], 1u);
          }
        } else if (valid) {
          float e = expf(l[i][j] - M[i]);
          float v = e * inv[i];
          unsigned bits = __float_as_uint(v);
          if (MODE == 1) {
            if ((bits >> 20) == pf) atomicAdd(&hloc[(bits >> 8) & 0xFFFu], 1u);
          } else {
            if ((bits >> 8) == pf) atomicAdd(&hloc[bits & 0xFFu], 1u);
          }
        }
      }
    }
  }
  __syncthreads();
  for (int i = t; i < HB; i += 256)
    if (hloc[i]) atomicAdd(&hist_out[(size_t)bh * HB + i], hloc[i]);
}

// ------------------------------------------------------ radix-select levels
__global__ __launch_bounds__(64) void select_level(
    const unsigned* __restrict__ hist, int nbins,
    const unsigned* __restrict__ krem_in, const unsigned* __restrict__ pfx_in,
    unsigned* __restrict__ krem_out, unsigned* __restrict__ pfx_out, int shift) {
  const int bh = blockIdx.x;
  const int l = threadIdx.x;
  const int seg = nbins / 64;
  const unsigned krem = krem_in ? krem_in[bh] : KIDX_;
  const unsigned* hb = hist + (size_t)bh * nbins;
  __shared__ unsigned ps[64];
  unsigned psum = 0;
  int hi = nbins - 1 - l * seg;
  for (int i = 0; i < seg; i++) psum += hb[hi - i];
  ps[l] = psum;
  __syncthreads();
  if (l == 0) {
    unsigned cum = 0, before = 0;
    int bin = 0;
    for (int j = 0; j < 64; j++) {
      if (cum + ps[j] > krem) {
        unsigned c = cum;
        int hj = nbins - 1 - j * seg;
        for (int i = 0; i < seg; i++) {
          unsigned cnt = hb[hj - i];
          if (c + cnt > krem) { bin = hj - i; before = c; break; }
          c += cnt;
        }
        break;
      }
      cum += ps[j];
    }
    unsigned p = pfx_in ? pfx_in[bh] : 0u;
    pfx_out[bh] = (p << shift) | (unsigned)bin;
    krem_out[bh] = krem - before;
  }
}

// ------------------------------------------------- token ranking (stable)
__global__ __launch_bounds__(576) void rank_kernel(
    const float* __restrict__ ldiag, const float* __restrict__ rowmax_g,
    const float* __restrict__ rowsum_g, const unsigned* __restrict__ sigbits,
    int* __restrict__ kept) {
  const int b = blockIdx.x;
  const int i = threadIdx.x;  // token i+1
  __shared__ float sc[576];
  float s = 0.f;
  for (int h = 0; h < H_; h++) {
    int bh = b * H_ + h;
    float l = ldiag[(size_t)bh * N_ + (i + 1)];
    float M = rowmax_g[(size_t)bh * N_ + (i + 1)];
    float inv = 1.f / rowsum_g[(size_t)bh * N_ + (i + 1)];
    float e = expf(l - M);
    float v = e * inv;   // bit-identical to hist/AV computation
    float sg = __uint_as_float(sigbits[bh]);
    if (v >= sg) s = fmaxf(s, v);
  }
  sc[i] = s;
  __syncthreads();
  int r = 0;
  for (int j = 0; j < 576; j++) {
    float sj = sc[j];
    if (sj > s || (sj == s && j < i)) r++;
  }
  if (r < KK_ - 1) kept[b * KK_ + r + 1] = i + 1;
  if (i == 0) kept[b * KK_] = 0;
}

// ------------------------------------------------------ gather x_original
__global__ __launch_bounds__(256) void gather_x(
    const float* __restrict__ xo, const int* __restrict__ kept,
    float* __restrict__ out2) {
  const int bp = blockIdx.x;
  const int b = bp / KK_, p = bp % KK_;
  const int src = kept[b * KK_ + p];
  const float* s = xo + ((size_t)b * N_ + src) * C_;
  float* d = out2 + (size_t)bp * C_;
  for (int c = threadIdx.x; c < C_; c += 256) d[c] = s[c];
}

// ------------------------------------------- AV (QK recompute + PV)
__global__ __launch_bounds__(256) void av_kernel(
    const float* __restrict__ qb, const float* __restrict__ kb,
    const float* __restrict__ vb, const int* __restrict__ kept,
    const float* __restrict__ rowmax_g, const float* __restrict__ rowsum_g,
    const unsigned* __restrict__ sigbits, float* __restrict__ out1) {
  __shared__ __align__(16) float Qs[64][68];
  __shared__ __align__(16) float Ksf[64][68];   // K, then P overlay
  __shared__ __align__(16) float Vs[64][68];
  __shared__ int ridx[64];
  __shared__ float Ml[64], Il[64];
  const int bh = blockIdx.x;
  const int p0 = blockIdx.y * 64;
  const int b = bh / H_, h = bh % H_;
  const float sigma = __uint_as_float(sigbits[bh]);
  const int t = threadIdx.x;
  const int tx = t & 15, ty = t >> 4;
  if (t < 64) {
    int pp = p0 + t;
    int r = (pp < KK_) ? kept[b * KK_ + pp] : 0;
    ridx[t] = r;
    Ml[t] = rowmax_g[(size_t)bh * N_ + r];
    Il[t] = 1.f / rowsum_g[(size_t)bh * N_ + r];
  }
  __syncthreads();
  {
    const int c = t & 15, r0 = t >> 4;
#pragma unroll
    for (int s = 0; s < 4; s++) {
      int r = r0 + 16 * s;
      int gq = ridx[r];
      float4 v = *(const float4*)&qb[((size_t)bh * N_ + gq) * HD_ + 4 * c];
      v.x *= 0.125f; v.y *= 0.125f; v.z *= 0.125f; v.w *= 0.125f;
      *(float4*)&Qs[r][4 * c] = v;
    }
  }
  float M[4], inv[4];
#pragma unroll
  for (int i = 0; i < 4; i++) { int row = tx + 16 * i; M[i] = Ml[row]; inv[i] = Il[row]; }
  float acc[4][4] = {};
  for (int n0 = 0; n0 < N_; n0 += 64) {
    __syncthreads();
    {
      const int c = t & 15, r0 = t >> 4;
#pragma unroll
      for (int s = 0; s < 4; s++) {
        int r = r0 + 16 * s;
        int gn = n0 + r;
        float4 kv = make_float4(0.f, 0.f, 0.f, 0.f);
        float4 vv = make_float4(0.f, 0.f, 0.f, 0.f);
        if (gn < N_) {
          kv = *(const float4*)&kb[((size_t)bh * N_ + gn) * HD_ + 4 * c];
          vv = *(const float4*)&vb[((size_t)bh * N_ + gn) * HD_ + 4 * c];
        }
        *(float4*)&Ksf[r][4 * c] = kv;
        *(float4*)&Vs[r][4 * c] = vv;
      }
    }
    __syncthreads();
    float l[4][4];
#pragma unroll
    for (int i = 0; i < 4; i++)
#pragma unroll
      for (int j = 0; j < 4; j++) l[i][j] = 0.f;
#pragma unroll 4
    for (int d4 = 0; d4 < 16; d4++) {
      float4 a4[4], b4[4];
#pragma unroll
      for (int i = 0; i < 4; i++) a4[i] = *(const float4*)&Qs[tx + 16 * i][4 * d4];
#pragma unroll
      for (int j = 0; j < 4; j++) b4[j] = *(const float4*)&Ksf[4 * ty + j][4 * d4];
#pragma unroll
      for (int i = 0; i < 4; i++)
#pragma unroll
        for (int j = 0; j < 4; j++) fma4(a4[i], b4[j], l[i][j]);
    }
    __syncthreads();   // QK done -> overlay P on Ksf
#pragma unroll
    for (int i = 0; i < 4; i++) {
      float4 pv4;
      float* pp = (float*)&pv4;
#pragma unroll
      for (int j = 0; j < 4; j++) {
        float e = expf(l[i][j] - M[i]);
        float v = e * inv[i];
        pp[j] = (v >= sigma) ? v : 0.f;   // padded cols harmless: V=0
      }
      *(float4*)&Ksf[tx + 16 * i][4 * ty] = pv4;
    }
    __syncthreads();
#pragma unroll 4
    for (int nb = 0; nb < 16; nb++) {
      float4 pa4[4];
#pragma unroll
      for (int i = 0; i < 4; i++) pa4[i] = *(const float4*)&Ksf[tx + 16 * i][4 * nb];
#pragma unroll
      for (int e = 0; e < 4; e++) {
        float4 vv4 = *(const float4*)&Vs[4 * nb + e][4 * ty];
#pragma unroll
        for (int i = 0; i < 4; i++) {
          float pvv = ((const float*)&pa4[i])[e];
          acc[i][0] = __builtin_fmaf(pvv, vv4.x, acc[i][0]);
          acc[i][1] = __builtin_fmaf(pvv, vv4.y, acc[i][1]);
          acc[i][2] = __builtin_fmaf(pvv, vv4.z, acc[i][2]);
          acc[i][3] = __builtin_fmaf(pvv, vv4.w, acc[i][3]);
        }
      }
    }
  }
#pragma unroll
  for (int i = 0; i < 4; i++) {
    int pp = p0 + tx + 16 * i;
    if (pp >= KK_) continue;
    float4 o = make_float4(acc[i][0], acc[i][1], acc[i][2], acc[i][3]);
    *(float4*)&out1[((size_t)(b * KK_ + pp)) * C_ + h * HD_ + 4 * ty] = o;
  }
}

// ------------------------------------------- proj GEMM via bf16 MFMA
// out = Xi @ W^T + bias. 2-way hi/lo bf16 split, 3 MFMA terms (hh, hl, lh);
// error ~2^-17 relative — vastly under the 0.108 output threshold.
// Fragment layouts (16x16x32, m89-verified C/D; A/B canonical):
//   A: lane l holds A[row=l&15][k=(l>>4)*8 + 0..7]
//   B: lane l holds B[k=(l>>4)*8 + 0..7][col=l&15]
//   D: lane l, reg r -> D[row=(l>>4)*4+r][col=l&15]
__global__ __launch_bounds__(256) void proj_mfma(
    const float* __restrict__ Xi, const float* __restrict__ W,
    const float* __restrict__ bias, float* __restrict__ out) {
  // bf16 planes, rows padded to 40 shorts (80B: 16B-aligned, <=2-way banks)
  __shared__ __align__(16) short XsH[128][40];
  __shared__ __align__(16) short XsL[128][40];
  __shared__ __align__(16) short WsH[128][40];
  __shared__ __align__(16) short WsL[128][40];
  const int m0 = blockIdx.x * 128;
  const int n0 = blockIdx.y * 128;
  const int t = threadIdx.x;
  const int w = t >> 6;          // wave 0..3
  const int l = t & 63;          // lane
  const int wm = (w & 1) * 64;   // wave's m-offset in tile
  const int wn = (w >> 1) * 64;  // wave's n-offset in tile
  const int srow = t >> 1;             // staging row 0..127
  const int scol = (t & 1) * 16;       // staging col 0 or 16

  fx4 acc[4][4];
#pragma unroll
  for (int i = 0; i < 4; i++)
#pragma unroll
    for (int j = 0; j < 4; j++) acc[i][j] = (fx4){0.f, 0.f, 0.f, 0.f};

  for (int k0 = 0; k0 < 768; k0 += 32) {
    __syncthreads();
    {
      const float* xsrc = &Xi[(size_t)(m0 + srow) * 768 + k0 + scol];
      const float* wsrc = &W[(size_t)(n0 + srow) * 768 + k0 + scol];
      short hx[16], lx[16], hw[16], lw[16];
#pragma unroll
      for (int u = 0; u < 16; u += 4) {
        float4 xv = *(const float4*)&xsrc[u];
        float4 wv = *(const float4*)&wsrc[u];
        const float* xp = (const float*)&xv;
        const float* wp = (const float*)&wv;
#pragma unroll
        for (int e = 0; e < 4; e++) {
          unsigned short h = f2bf(xp[e]);
          hx[u + e] = (short)h;
          lx[u + e] = (short)f2bf(xp[e] - bf2f(h));
          unsigned short g = f2bf(wp[e]);
          hw[u + e] = (short)g;
          lw[u + e] = (short)f2bf(wp[e] - bf2f(g));
        }
      }
      *(bfx8*)&XsH[srow][scol]     = *(bfx8*)&hx[0];
      *(bfx8*)&XsH[srow][scol + 8] = *(bfx8*)&hx[8];
      *(bfx8*)&XsL[srow][scol]     = *(bfx8*)&lx[0];
      *(bfx8*)&XsL[srow][scol + 8] = *(bfx8*)&lx[8];
      *(bfx8*)&WsH[srow][scol]     = *(bfx8*)&hw[0];
      *(bfx8*)&WsH[srow][scol + 8] = *(bfx8*)&hw[8];
      *(bfx8*)&WsL[srow][scol]     = *(bfx8*)&lw[0];
      *(bfx8*)&WsL[srow][scol + 8] = *(bfx8*)&lw[8];
    }
    __syncthreads();
    bfx8 aH[4], aL[4];
    const int ar = l & 15, ak = (l >> 4) * 8;
#pragma unroll
    for (int i = 0; i < 4; i++) {
      aH[i] = *(const bfx8*)&XsH[wm + 16 * i + ar][ak];
      aL[i] = *(const bfx8*)&XsL[wm + 16 * i + ar][ak];
    }
#pragma unroll
    for (int j = 0; j < 4; j++) {
      bfx8 bH = *(const bfx8*)&WsH[wn + 16 * j + ar][ak];
      bfx8 bL = *(const bfx8*)&WsL[wn + 16 * j + ar][ak];
#pragma unroll
      for (int i = 0; i < 4; i++) {
        acc[i][j] = __builtin_amdgcn_mfma_f32_16x16x32_bf16(aH[i], bH, acc[i][j], 0, 0, 0);
        acc[i][j] = __builtin_amdgcn_mfma_f32_16x16x32_bf16(aH[i], bL, acc[i][j], 0, 0, 0);
        acc[i][j] = __builtin_amdgcn_mfma_f32_16x16x32_bf16(aL[i], bH, acc[i][j], 0, 0, 0);
      }
    }
  }
  // epilogue: D layout col=l&15, row=(l>>4)*4+r
  const int dc = l & 15, dr4 = (l >> 4) * 4;
#pragma unroll
  for (int j = 0; j < 4; j++) {
    int col = n0 + wn + 16 * j + dc;
    float bb = bias[col];
#pragma unroll
    for (int i = 0; i < 4; i++) {
#pragma unroll
      for (int r = 0; r < 4; r++) {
        int row = m0 + wm + 16 * i + dr4 + r;   // M2=8320=65*128, no guard
        out[(size_t)row * C_ + col] = acc[i][j][r] + bb;
      }
    }
  }
}

// ---------------------------------------------------------------- launcher
extern "C" void kernel_launch(void* const* d_in, const int* in_sizes, int n_in,
                              void* d_out, int out_size, void* d_ws, size_t ws_size,
                              hipStream_t stream) {
  (void)in_sizes; (void)n_in; (void)out_size; (void)ws_size;
  const float* x    = (const float*)d_in[0];
  const float* xo   = (const float*)d_in[1];
  const float* qkvw = (const float*)d_in[2];
  const float* pw   = (const float*)d_in[3];
  const float* pb   = (const float*)d_in[4];

  char* ws = (char*)d_ws;
  size_t off = 0;
  auto alloc = [&](size_t bytes) -> char* {
    char* p = ws + off;
    off += (bytes + 255) & ~(size_t)255;
    return p;
  };
  const size_t szQ    = (size_t)BH_ * N_ * HD_ * 4;   // 28.4 MB
  const size_t szOut1 = (size_t)M2_ * C_ * 4;         // 25.6 MB
  const size_t szRow  = (size_t)BH_ * N_ * 4;         // 443 KB
  const size_t szH12  = (size_t)BH_ * 4096 * 4;       // 3.1 MB
  const size_t szH3   = (size_t)BH_ * 256 * 4;

  float* qb     = (float*)alloc(szQ);
  float* kb     = (float*)alloc(szQ);
  float* vb     = (float*)alloc(szQ);
  float* out1   = (float*)alloc(szOut1);
  float* ldiag  = (float*)alloc(szRow);
  float* rowmax = (float*)alloc(szRow);
  float* rowsum = (float*)alloc(szRow);
  unsigned* hist1 = (unsigned*)alloc(szH12);
  unsigned* hist2 = (unsigned*)alloc(szH12);
  unsigned* hist3 = (unsigned*)alloc(szH3);
  unsigned* pfx1  = (unsigned*)alloc(BH_ * 4);
  unsigned* krem1 = (unsigned*)alloc(BH_ * 4);
  unsigned* pfx2  = (unsigned*)alloc(BH_ * 4);
  unsigned* krem2 = (unsigned*)alloc(BH_ * 4);
  unsigned* sigb  = (unsigned*)alloc(BH_ * 4);
  unsigned* krem3 = (unsigned*)alloc(BH_ * 4);
  int* kept       = (int*)alloc((size_t)B_ * KK_ * 4);

  hipMemsetAsync(hist1, 0, szH12, stream);
  hipMemsetAsync(hist2, 0, szH12, stream);
  hipMemsetAsync(hist3, 0, szH3, stream);

  qkv_gemm<<<dim3(145, 18), 256, 0, stream>>>(x, qkvw, qb, kb, vb);
  attn_stats<<<dim3(BH_, 10), 256, 0, stream>>>(qb, kb, rowmax, rowsum, ldiag);
  hist_pass<0><<<dim3(BH_, 10), 256, 0, stream>>>(qb, kb, rowmax, rowsum, nullptr, hist1);
  select_level<<<BH_, 64, 0, stream>>>(hist1, 4096, nullptr, nullptr, krem1, pfx1, 12);
  hist_pass<1><<<dim3(BH_, 10), 256, 0, stream>>>(qb, kb, rowmax, rowsum, pfx1, hist2);
  select_level<<<BH_, 64, 0, stream>>>(hist2, 4096, krem1, pfx1, krem2, pfx2, 12);
  hist_pass<2><<<dim3(BH_, 10), 256, 0, stream>>>(qb, kb, rowmax, rowsum, pfx2, hist3);
  select_level<<<BH_, 64, 0, stream>>>(hist3, 256, krem2, pfx2, krem3, sigb, 8);
  rank_kernel<<<B_, 576, 0, stream>>>(ldiag, rowmax, rowsum, sigb, kept);

  float* outp = (float*)d_out;
  gather_x<<<M2_, 256, 0, stream>>>(xo, kept, outp + (size_t)M2_ * C_);
  av_kernel<<<dim3(BH_, 9), 256, 0, stream>>>(qb, kb, vb, kept, rowmax, rowsum, sigb, out1);
  proj_mfma<<<dim3(65, 6), 256, 0, stream>>>(out1, pw, pb, outp);
}